// Round 6
// baseline (679.532 us; speedup 1.0000x reference)
//
#include <hip/hip_runtime.h>
#include <math.h>

// Problem constants
#define NSEQ 8192          // B*N
#define PATCHL 16
#define HIDN 256
#define VOCABN 256

typedef __attribute__((ext_vector_type(4))) float f32x4;
typedef __attribute__((ext_vector_type(8))) short bf16x8;   // 8 bf16 = 4 VGPRs

__device__ __forceinline__ unsigned short f2bf(float f) {
    unsigned int x = __float_as_uint(f);
    unsigned int r = (x + 0x7fffu + ((x >> 16) & 1u)) >> 16;
    return (unsigned short)r;
}
__device__ __forceinline__ float bf2f(unsigned short b) {
    return __uint_as_float(((unsigned int)b) << 16);
}
__device__ __forceinline__ float sigf(float x)   { return 1.f / (1.f + __expf(-x)); }
__device__ __forceinline__ float tanhf_(float x) { return 2.f / (1.f + __expf(-2.f * x)) - 1.f; }

// ---------------------------------------------------------------------------
// Fragment-order bf16 pack of a weight matrix slice (MFMA B operand).
// ---------------------------------------------------------------------------
__global__ __launch_bounds__(256)
void pack_frag(const float* __restrict__ src, int ld, int col0, int nks,
               unsigned short* __restrict__ dst)
{
    const int g = blockIdx.x * 256 + threadIdx.x;
    const int lane = g & 63;
    const int ks = (g / 64) % nks;
    const int T  = g / (64 * nks);
    const float* s = src + (size_t)(T * 16 + (lane & 15)) * ld + col0 + ks * 32 + ((lane >> 4) & 3) * 8;
    unsigned int q[4];
#pragma unroll
    for (int j = 0; j < 4; j++) {
        unsigned int lo = f2bf(s[2 * j]);
        unsigned int hi = f2bf(s[2 * j + 1]);
        q[j] = lo | (hi << 16);
    }
    uint4 v; v.x = q[0]; v.y = q[1]; v.z = q[2]; v.w = q[3];
    *(uint4*)(dst + (size_t)g * 8) = v;
}

// ---------------------------------------------------------------------------
// bf16 MFMA GEMM: C[m][n] = sum_k A[m][k] * W[n][k] (+bias[n])
// BM=128 BN=64 BK=64, 512 threads (8 waves). Verified rounds 3-5.
// ---------------------------------------------------------------------------
template<bool ASRC_BF16, bool OUT_BF16>
__global__ __launch_bounds__(512)
void gemm_mfma(const void* __restrict__ Asrc, int lda,
               const unsigned short* __restrict__ bpack, int nks_total,
               const float* __restrict__ bias, void* __restrict__ Cdst, int ldc,
               int K)
{
    const int tid = threadIdx.x;
    const int w = tid >> 6, lane = tid & 63;
    const int l15 = lane & 15, kg = (lane >> 4) & 3;
    const int bm = blockIdx.x * 128, bn = blockIdx.y * 64;

    __shared__ unsigned short As[2][128 * 64];

    const int srow = tid >> 2;           // 0..127
    const int scol = (tid & 3) * 16;     // 0,16,32,48
    const int nkt = K / 64;

    f32x4 acc[4];
#pragma unroll
    for (int nt = 0; nt < 4; nt++) acc[nt] = 0.f;

    const int wb0 = srow * 128 + ((scol * 2) ^ ((srow & 7) << 4));
    const int wb1 = srow * 128 + ((scol * 2 + 16) ^ ((srow & 7) << 4));

#define STAGE(kt, buf) do {                                                         \
        const int gk = (kt) * 64 + scol;                                            \
        unsigned short tmp[16];                                                     \
        if (ASRC_BF16) {                                                            \
            const unsigned short* A = (const unsigned short*)Asrc;                  \
            *(uint4*)(tmp)     = *(const uint4*)(A + (size_t)(bm + srow) * lda + gk);      \
            *(uint4*)(tmp + 8) = *(const uint4*)(A + (size_t)(bm + srow) * lda + gk + 8);  \
        } else {                                                                    \
            const float* A = (const float*)Asrc;                                    \
            const float4 a0 = *(const float4*)(A + (size_t)(bm + srow) * lda + gk);       \
            const float4 a1 = *(const float4*)(A + (size_t)(bm + srow) * lda + gk + 4);   \
            const float4 a2 = *(const float4*)(A + (size_t)(bm + srow) * lda + gk + 8);   \
            const float4 a3 = *(const float4*)(A + (size_t)(bm + srow) * lda + gk + 12);  \
            tmp[0] = f2bf(a0.x);  tmp[1] = f2bf(a0.y);  tmp[2] = f2bf(a0.z);  tmp[3] = f2bf(a0.w);   \
            tmp[4] = f2bf(a1.x);  tmp[5] = f2bf(a1.y);  tmp[6] = f2bf(a1.z);  tmp[7] = f2bf(a1.w);   \
            tmp[8] = f2bf(a2.x);  tmp[9] = f2bf(a2.y);  tmp[10] = f2bf(a2.z); tmp[11] = f2bf(a2.w);  \
            tmp[12] = f2bf(a3.x); tmp[13] = f2bf(a3.y); tmp[14] = f2bf(a3.z); tmp[15] = f2bf(a3.w);  \
        }                                                                           \
        *(uint4*)((char*)As[buf] + wb0) = *(uint4*)tmp;                             \
        *(uint4*)((char*)As[buf] + wb1) = *(uint4*)(tmp + 8);                       \
    } while (0)

    STAGE(0, 0);
    __syncthreads();

    for (int kt = 0; kt < nkt; ++kt) {
        if (kt + 1 < nkt) STAGE(kt + 1, (kt + 1) & 1);
        const unsigned short* buf = As[kt & 1];
        const int row = w * 16 + l15;
#pragma unroll
        for (int ks = 0; ks < 2; ++ks) {
            const int bo = row * 128 + (((ks * 64) + kg * 16) ^ ((row & 7) << 4));
            const bf16x8 a = *(const bf16x8*)((const char*)buf + bo);
#pragma unroll
            for (int nt = 0; nt < 4; ++nt) {
                const int T = blockIdx.y * 4 + nt;
                const bf16x8 b = *(const bf16x8*)(bpack + (((size_t)T * nks_total + (kt * 2 + ks)) * 64 + lane) * 8);
                acc[nt] = __builtin_amdgcn_mfma_f32_16x16x32_bf16(a, b, acc[nt], 0, 0, 0);
            }
        }
        __syncthreads();
    }
#undef STAGE

#pragma unroll
    for (int nt = 0; nt < 4; ++nt) {
        const int n = bn + nt * 16 + l15;
        const float bv = bias ? bias[n] : 0.f;
#pragma unroll
        for (int rr = 0; rr < 4; ++rr) {
            const int m = bm + w * 16 + kg * 4 + rr;
            const float v = acc[nt][rr] + bv;
            if (OUT_BF16) ((unsigned short*)Cdst)[(size_t)m * ldc + n] = f2bf(v);
            else          ((float*)Cdst)[(size_t)m * ldc + n] = v;
        }
    }
}

// ---------------------------------------------------------------------------
// Fused GRU scan (producer folded in). 32 seqs/block, 512 threads, 2 blk/CU.
// Per step p:
//   1. stage PMs[sl][0:768] = premixB[byte(sl,p)]  (coalesced row bursts, L2)
//   2. copy h(p-1) LDS->hh (coalesced)   [p>0]
//   3. MFMA recurrence reads H=h(p-1)    [p>0]
//   4. barrier  (PMs ready; H reads done)
//   5. gates: xg = latg(regs) + PMs(LDS); write h(p) into H (single buffer)
//   6. barrier
// latg pre-activations (step-invariant) live in 48 registers/thread (r3-style).
// ---------------------------------------------------------------------------
#define PMS 776   // padded row stride (shorts)
__global__ __launch_bounds__(512, 4)
void gru_scan_fused(const int* __restrict__ bytes,         // [NSEQ*16]
                    const float* __restrict__ latg,        // [NSEQ][768] (incl b_ih)
                    const unsigned short* __restrict__ premixB, // [256][768] bf16
                    const unsigned short* __restrict__ wpack,   // 48 gate tiles
                    const float* __restrict__ b_hh,        // [768]
                    unsigned short* __restrict__ hh,       // [SPC*16][256] bf16
                    int seq0)
{
    const int tid  = threadIdx.x;
    const int w    = tid >> 6;
    const int lane = tid & 63;
    const int l15  = lane & 15;
    const int kg   = (lane >> 4) & 3;
    const int s0l  = blockIdx.x * 32;            // chunk-local
    const int s0g  = seq0 + s0l;                 // global

    __shared__ unsigned short PMs[32 * PMS];     // 49.7 KB
    __shared__ unsigned short H[32 * 256];       // 16 KB
    __shared__ int BYs[512];                     // 2 KB

    BYs[tid] = bytes[(size_t)s0g * PATCHL + tid];

    float bhr[2], bhz[2], bhn[2];
#pragma unroll
    for (int nt = 0; nt < 2; nt++) {
        const int u = w * 32 + nt * 16 + l15;
        bhr[nt] = b_hh[u]; bhz[nt] = b_hh[256 + u]; bhn[nt] = b_hh[512 + u];
    }

    // step-invariant gate pre-activations -> registers (recurrent bias folded
    // into r,z; n keeps bhn separate since n = tanh(xn + r*(accn+bhn)))
    float lgr[2][2][4], lgz[2][2][4], lgn[2][2][4];
#pragma unroll
    for (int mt = 0; mt < 2; mt++)
#pragma unroll
        for (int nt = 0; nt < 2; nt++) {
            const int u = w * 32 + nt * 16 + l15;
#pragma unroll
            for (int rr = 0; rr < 4; rr++) {
                const int sg = s0g + mt * 16 + kg * 4 + rr;
                const float* lg = latg + (size_t)sg * 768;
                lgr[mt][nt][rr] = lg[u]       + bhr[nt];
                lgz[mt][nt][rr] = lg[u + 256] + bhz[nt];
                lgn[mt][nt][rr] = lg[u + 512];
            }
        }

    float hreg[2][2][4];
#pragma unroll
    for (int mt = 0; mt < 2; mt++)
#pragma unroll
        for (int nt = 0; nt < 2; nt++)
#pragma unroll
            for (int rr = 0; rr < 4; rr++) hreg[mt][nt][rr] = 0.f;

    __syncthreads();    // BYs ready

    for (int p = 0; p < PATCHL; ++p) {
        // ---- 1. stage premix rows for this step's bytes (L2 -> LDS) ----
#pragma unroll
        for (int j = 0; j < 6; ++j) {
            const int idx = j * 512 + tid;          // uint4 index; 96 per row
            const int row = idx / 96, col = idx - row * 96;
            const int bv = p ? BYs[row * PATCHL + p - 1] : 0;
            *(uint4*)(PMs + row * PMS + col * 8) =
                *(const uint4*)(premixB + (size_t)bv * 768 + col * 8);
        }

        // ---- 2. coalesced hh write of h(p-1) (reads H, pre-overwrite) ----
        if (p) {
#pragma unroll
            for (int rj = 0; rj < 4; ++rj) {
                const int row = w * 4 + rj;
                const int boff = (lane * 8) ^ ((row & 7) << 4);   // un-swizzle
                const ushort4 v = *(const ushort4*)((const char*)(H + row * 256) + boff);
                *(ushort4*)(hh + ((size_t)(s0l + row) * PATCHL + (p - 1)) * 256 + lane * 4) = v;
            }
        }

        // ---- 3. recurrence: hg = h(p-1) @ W_hh^T ----
        f32x4 accr[2][2], accz[2][2], accn[2][2];
#pragma unroll
        for (int mt = 0; mt < 2; mt++)
#pragma unroll
            for (int nt = 0; nt < 2; nt++) {
                accr[mt][nt] = 0.f; accz[mt][nt] = 0.f; accn[mt][nt] = 0.f;
            }
        if (p != 0) {
#pragma unroll
            for (int ks = 0; ks < 8; ++ks) {
                bf16x8 a[2];
#pragma unroll
                for (int mt = 0; mt < 2; mt++) {
                    const int s = mt * 16 + l15;
                    const int off = (ks * 64 + kg * 16) ^ ((s & 7) << 4);
                    a[mt] = *(const bf16x8*)(H + s * 256 + (off >> 1));
                }
#pragma unroll
                for (int nt = 0; nt < 2; nt++) {
                    const int tb = w * 2 + nt;
                    const bf16x8 br = *(const bf16x8*)(wpack + (((size_t)(tb)      * 8 + ks) * 64 + lane) * 8);
                    const bf16x8 bz = *(const bf16x8*)(wpack + (((size_t)(16 + tb) * 8 + ks) * 64 + lane) * 8);
                    const bf16x8 bn = *(const bf16x8*)(wpack + (((size_t)(32 + tb) * 8 + ks) * 64 + lane) * 8);
#pragma unroll
                    for (int mt = 0; mt < 2; mt++) {
                        accr[mt][nt] = __builtin_amdgcn_mfma_f32_16x16x32_bf16(a[mt], br, accr[mt][nt], 0, 0, 0);
                        accz[mt][nt] = __builtin_amdgcn_mfma_f32_16x16x32_bf16(a[mt], bz, accz[mt][nt], 0, 0, 0);
                        accn[mt][nt] = __builtin_amdgcn_mfma_f32_16x16x32_bf16(a[mt], bn, accn[mt][nt], 0, 0, 0);
                    }
                }
            }
        }
        __syncthreads();   // PMs staged; all H reads (copy + MFMA) complete

        // ---- 5. gates + state update; write h(p) into H ----
#pragma unroll
        for (int mt = 0; mt < 2; mt++)
#pragma unroll
            for (int nt = 0; nt < 2; nt++) {
                const int u = w * 32 + nt * 16 + l15;
#pragma unroll
                for (int rr = 0; rr < 4; rr++) {
                    const int sl = mt * 16 + kg * 4 + rr;
                    const float xr = lgr[mt][nt][rr] + bf2f(PMs[sl * PMS + u]);
                    const float xz = lgz[mt][nt][rr] + bf2f(PMs[sl * PMS + 256 + u]);
                    const float xn = lgn[mt][nt][rr] + bf2f(PMs[sl * PMS + 512 + u]);
                    const float r = sigf(xr + accr[mt][nt][rr]);
                    const float z = sigf(xz + accz[mt][nt][rr]);
                    const float n = tanhf_(xn + r * (accn[mt][nt][rr] + bhn[nt]));
                    const float hn_ = (1.f - z) * n + z * hreg[mt][nt][rr];
                    hreg[mt][nt][rr] = hn_;
                    const int bo = (2 * u) ^ ((sl & 7) << 4);
                    H[sl * 256 + (bo >> 1)] = f2bf(hn_);
                }
            }
        __syncthreads();   // h(p) visible
    }

    // ---- final hh write for p = 15 ----
#pragma unroll
    for (int rj = 0; rj < 4; ++rj) {
        const int row = w * 4 + rj;
        const int boff = (lane * 8) ^ ((row & 7) << 4);
        const ushort4 v = *(const ushort4*)((const char*)(H + row * 256) + boff);
        *(ushort4*)(hh + ((size_t)(s0l + row) * PATCHL + (PATCHL - 1)) * 256 + lane * 4) = v;
    }
}

// ---------------------------------------------------------------------------
extern "C" void kernel_launch(void* const* d_in, const int* in_sizes, int n_in,
                              void* d_out, int out_size, void* d_ws, size_t ws_size,
                              hipStream_t stream)
{
    const float* latents = (const float*)d_in[0];   // [8192][1024]
    const int*   tb      = (const int*)d_in[1];     // [8192*16]
    const float* W_proj  = (const float*)d_in[2];   // [256][1024]
    const float* b_proj  = (const float*)d_in[3];   // [256]
    const float* emb     = (const float*)d_in[4];   // [256][256]
    const float* W_ih    = (const float*)d_in[5];   // [768][512]
    const float* W_hh    = (const float*)d_in[6];   // [768][256]
    const float* b_ih    = (const float*)d_in[7];   // [768]
    const float* b_hh    = (const float*)d_in[8];   // [768]
    const float* W_head  = (const float*)d_in[9];   // [256][256]
    const float* b_head  = (const float*)d_in[10];  // [256]
    float* out = (float*)d_out;

    // ---- workspace layout (bytes) ----
    char* w = (char*)d_ws;
    float* latg = (float*)w;                               w += (size_t)NSEQ * 768 * 4;     // 25.2 MB
    unsigned short* ctxb    = (unsigned short*)w;          w += (size_t)NSEQ * HIDN * 2;    // 4.2 MB
    unsigned short* premixB = (unsigned short*)w;          w += 256 * 768 * 2;
    unsigned short* bpack1  = (unsigned short*)w;          w += 16 * 32 * 64 * 8 * 2;
    unsigned short* bpack2  = (unsigned short*)w;          w += 48 * 8 * 64 * 8 * 2;
    unsigned short* bpack3  = (unsigned short*)w;          w += 48 * 8 * 64 * 8 * 2;
    unsigned short* wpackG  = (unsigned short*)w;          w += 48 * 8 * 64 * 8 * 2;        // gates
    unsigned short* bpackH  = (unsigned short*)w;          w += 16 * 8 * 64 * 8 * 2;        // head
    unsigned short* hh_c    = (unsigned short*)w;
    const size_t fixed_bytes = (size_t)(w - (char*)d_ws);
    const size_t chunk_full  = (size_t)NSEQ * PATCHL * 256 * 2;          // hh = 67 MB

    int nch = 1;
    while (nch < 16 && fixed_bytes + chunk_full / nch > ws_size) nch <<= 1;
    const int SPC = NSEQ / nch;                    // seqs per chunk

    // ---- weight packs (fragment-ordered bf16) ----
    hipLaunchKernelGGL(pack_frag, dim3(128), dim3(256), 0, stream, W_proj, 1024, 0, 32, bpack1);
    hipLaunchKernelGGL(pack_frag, dim3(96),  dim3(256), 0, stream, W_ih,   512, 256, 8, bpack2);
    hipLaunchKernelGGL(pack_frag, dim3(96),  dim3(256), 0, stream, W_ih,   512, 0,   8, bpack3);
    hipLaunchKernelGGL(pack_frag, dim3(96),  dim3(256), 0, stream, W_hh,   256, 0,   8, wpackG);
    hipLaunchKernelGGL(pack_frag, dim3(32),  dim3(256), 0, stream, W_head, 256, 0,   8, bpackH);

    // premixB(bf16) = emb @ W_ih[:,0:256]^T        [256][768]
    hipLaunchKernelGGL((gemm_mfma<false, true>), dim3(2, 12), dim3(512), 0, stream,
                       emb, 256, bpack3, 8, nullptr, premixB, 768, 256);
    // ctx(bf16) = latents @ W_proj^T + b_proj      [8192][256]
    hipLaunchKernelGGL((gemm_mfma<false, true>), dim3(NSEQ / 128, 4), dim3(512), 0, stream,
                       latents, 1024, bpack1, 32, b_proj, ctxb, 256, 1024);
    // latg(f32) = ctx @ W_ih[:,256:512]^T + b_ih   [8192][768]
    hipLaunchKernelGGL((gemm_mfma<true, false>), dim3(NSEQ / 128, 12), dim3(512), 0, stream,
                       ctxb, 256, bpack2, 8, b_ih, latg, 768, 256);

    // ---- per-chunk: fused scan -> head GEMM (stream-ordered) ----
    for (int c = 0; c < nch; ++c) {
        const int seq0 = c * SPC;
        hipLaunchKernelGGL(gru_scan_fused, dim3(SPC / 32), dim3(512), 0, stream,
                           tb, latg, premixB, wpackG, b_hh, hh_c, seq0);
        // logits = h_hist @ W_head^T + b_head    [SPC*16][256]
        hipLaunchKernelGGL((gemm_mfma<true, false>), dim3(SPC * PATCHL / 128, 4), dim3(512), 0, stream,
                           hh_c, 256, bpackH, 8, b_head,
                           out + (size_t)seq0 * PATCHL * VOCABN, 256, 256);
    }
}

// Round 7
// 409.119 us; speedup vs baseline: 1.6610x; 1.6610x over previous
//
#include <hip/hip_runtime.h>
#include <math.h>

// Problem constants
#define NSEQ 8192          // B*N
#define PATCHL 16
#define HIDN 256
#define VOCABN 256

typedef __attribute__((ext_vector_type(4))) float f32x4;
typedef __attribute__((ext_vector_type(8))) short bf16x8;   // 8 bf16 = 4 VGPRs

__device__ __forceinline__ unsigned short f2bf(float f) {
    unsigned int x = __float_as_uint(f);
    unsigned int r = (x + 0x7fffu + ((x >> 16) & 1u)) >> 16;
    return (unsigned short)r;
}
__device__ __forceinline__ float bf2f(unsigned short b) {
    return __uint_as_float(((unsigned int)b) << 16);
}
__device__ __forceinline__ float sigf(float x)   { return 1.f / (1.f + __expf(-x)); }
__device__ __forceinline__ float tanhf_(float x) { return 2.f / (1.f + __expf(-2.f * x)) - 1.f; }

// ---------------------------------------------------------------------------
// Fragment-order bf16 pack of a weight matrix slice (MFMA B operand).
// ---------------------------------------------------------------------------
__global__ __launch_bounds__(256)
void pack_frag(const float* __restrict__ src, int ld, int col0, int nks,
               unsigned short* __restrict__ dst)
{
    const int g = blockIdx.x * 256 + threadIdx.x;
    const int lane = g & 63;
    const int ks = (g / 64) % nks;
    const int T  = g / (64 * nks);
    const float* s = src + (size_t)(T * 16 + (lane & 15)) * ld + col0 + ks * 32 + ((lane >> 4) & 3) * 8;
    unsigned int q[4];
#pragma unroll
    for (int j = 0; j < 4; j++) {
        unsigned int lo = f2bf(s[2 * j]);
        unsigned int hi = f2bf(s[2 * j + 1]);
        q[j] = lo | (hi << 16);
    }
    uint4 v; v.x = q[0]; v.y = q[1]; v.z = q[2]; v.w = q[3];
    *(uint4*)(dst + (size_t)g * 8) = v;
}

// ---------------------------------------------------------------------------
// bf16 MFMA GEMM: C[m][n] = sum_k A[m][k] * W[n][k] (+bias[n])
// BM=128 BN=64 BK=64, 512 threads (8 waves). Verified rounds 3-6.
// ---------------------------------------------------------------------------
template<bool ASRC_BF16, bool OUT_BF16>
__global__ __launch_bounds__(512)
void gemm_mfma(const void* __restrict__ Asrc, int lda,
               const unsigned short* __restrict__ bpack, int nks_total,
               const float* __restrict__ bias, void* __restrict__ Cdst, int ldc,
               int K)
{
    const int tid = threadIdx.x;
    const int w = tid >> 6, lane = tid & 63;
    const int l15 = lane & 15, kg = (lane >> 4) & 3;
    const int bm = blockIdx.x * 128, bn = blockIdx.y * 64;

    __shared__ unsigned short As[2][128 * 64];

    const int srow = tid >> 2;           // 0..127
    const int scol = (tid & 3) * 16;     // 0,16,32,48
    const int nkt = K / 64;

    f32x4 acc[4];
#pragma unroll
    for (int nt = 0; nt < 4; nt++) acc[nt] = 0.f;

    const int wb0 = srow * 128 + ((scol * 2) ^ ((srow & 7) << 4));
    const int wb1 = srow * 128 + ((scol * 2 + 16) ^ ((srow & 7) << 4));

#define STAGE(kt, buf) do {                                                         \
        const int gk = (kt) * 64 + scol;                                            \
        unsigned short tmp[16];                                                     \
        if (ASRC_BF16) {                                                            \
            const unsigned short* A = (const unsigned short*)Asrc;                  \
            *(uint4*)(tmp)     = *(const uint4*)(A + (size_t)(bm + srow) * lda + gk);      \
            *(uint4*)(tmp + 8) = *(const uint4*)(A + (size_t)(bm + srow) * lda + gk + 8);  \
        } else {                                                                    \
            const float* A = (const float*)Asrc;                                    \
            const float4 a0 = *(const float4*)(A + (size_t)(bm + srow) * lda + gk);       \
            const float4 a1 = *(const float4*)(A + (size_t)(bm + srow) * lda + gk + 4);   \
            const float4 a2 = *(const float4*)(A + (size_t)(bm + srow) * lda + gk + 8);   \
            const float4 a3 = *(const float4*)(A + (size_t)(bm + srow) * lda + gk + 12);  \
            tmp[0] = f2bf(a0.x);  tmp[1] = f2bf(a0.y);  tmp[2] = f2bf(a0.z);  tmp[3] = f2bf(a0.w);   \
            tmp[4] = f2bf(a1.x);  tmp[5] = f2bf(a1.y);  tmp[6] = f2bf(a1.z);  tmp[7] = f2bf(a1.w);   \
            tmp[8] = f2bf(a2.x);  tmp[9] = f2bf(a2.y);  tmp[10] = f2bf(a2.z); tmp[11] = f2bf(a2.w);  \
            tmp[12] = f2bf(a3.x); tmp[13] = f2bf(a3.y); tmp[14] = f2bf(a3.z); tmp[15] = f2bf(a3.w);  \
        }                                                                           \
        *(uint4*)((char*)As[buf] + wb0) = *(uint4*)tmp;                             \
        *(uint4*)((char*)As[buf] + wb1) = *(uint4*)(tmp + 8);                       \
    } while (0)

    STAGE(0, 0);
    __syncthreads();

    for (int kt = 0; kt < nkt; ++kt) {
        if (kt + 1 < nkt) STAGE(kt + 1, (kt + 1) & 1);
        const unsigned short* buf = As[kt & 1];
        const int row = w * 16 + l15;
#pragma unroll
        for (int ks = 0; ks < 2; ++ks) {
            const int bo = row * 128 + (((ks * 64) + kg * 16) ^ ((row & 7) << 4));
            const bf16x8 a = *(const bf16x8*)((const char*)buf + bo);
#pragma unroll
            for (int nt = 0; nt < 4; ++nt) {
                const int T = blockIdx.y * 4 + nt;
                const bf16x8 b = *(const bf16x8*)(bpack + (((size_t)T * nks_total + (kt * 2 + ks)) * 64 + lane) * 8);
                acc[nt] = __builtin_amdgcn_mfma_f32_16x16x32_bf16(a, b, acc[nt], 0, 0, 0);
            }
        }
        __syncthreads();
    }
#undef STAGE

#pragma unroll
    for (int nt = 0; nt < 4; ++nt) {
        const int n = bn + nt * 16 + l15;
        const float bv = bias ? bias[n] : 0.f;
#pragma unroll
        for (int rr = 0; rr < 4; ++rr) {
            const int m = bm + w * 16 + kg * 4 + rr;
            const float v = acc[nt][rr] + bv;
            if (OUT_BF16) ((unsigned short*)Cdst)[(size_t)m * ldc + n] = f2bf(v);
            else          ((float*)Cdst)[(size_t)m * ldc + n] = v;
        }
    }
}

// ---------------------------------------------------------------------------
// Fused GRU scan (r6 structure, verified correct). 32 seqs/block, 512 threads.
// __launch_bounds__(512) ONLY: no min-wave occupancy bound. r6's (512,4)
// capped VGPR at <=128 and spilled the ~170-reg payload to scratch (754 MB
// FETCH). Grid = 256 blocks = 1 block/CU either way, so the bound bought
// nothing. 256-VGPR cap -> no spill.
// ---------------------------------------------------------------------------
#define PMS 776   // padded row stride (shorts)
__global__ __launch_bounds__(512)
void gru_scan_fused(const int* __restrict__ bytes,         // [NSEQ*16]
                    const float* __restrict__ latg,        // [NSEQ][768] (incl b_ih)
                    const unsigned short* __restrict__ premixB, // [256][768] bf16
                    const unsigned short* __restrict__ wpack,   // 48 gate tiles
                    const float* __restrict__ b_hh,        // [768]
                    unsigned short* __restrict__ hh,       // [SPC*16][256] bf16
                    int seq0)
{
    const int tid  = threadIdx.x;
    const int w    = tid >> 6;
    const int lane = tid & 63;
    const int l15  = lane & 15;
    const int kg   = (lane >> 4) & 3;
    const int s0l  = blockIdx.x * 32;            // chunk-local
    const int s0g  = seq0 + s0l;                 // global

    __shared__ unsigned short PMs[32 * PMS];     // 49.7 KB
    __shared__ unsigned short H[32 * 256];       // 16 KB
    __shared__ int BYs[512];                     // 2 KB

    BYs[tid] = bytes[(size_t)s0g * PATCHL + tid];

    float bhr[2], bhz[2], bhn[2];
#pragma unroll
    for (int nt = 0; nt < 2; nt++) {
        const int u = w * 32 + nt * 16 + l15;
        bhr[nt] = b_hh[u]; bhz[nt] = b_hh[256 + u]; bhn[nt] = b_hh[512 + u];
    }

    // step-invariant gate pre-activations -> registers (recurrent bias folded
    // into r,z; n keeps bhn separate since n = tanh(xn + r*(accn+bhn)))
    float lgr[2][2][4], lgz[2][2][4], lgn[2][2][4];
#pragma unroll
    for (int mt = 0; mt < 2; mt++)
#pragma unroll
        for (int nt = 0; nt < 2; nt++) {
            const int u = w * 32 + nt * 16 + l15;
#pragma unroll
            for (int rr = 0; rr < 4; rr++) {
                const int sg = s0g + mt * 16 + kg * 4 + rr;
                const float* lg = latg + (size_t)sg * 768;
                lgr[mt][nt][rr] = lg[u]       + bhr[nt];
                lgz[mt][nt][rr] = lg[u + 256] + bhz[nt];
                lgn[mt][nt][rr] = lg[u + 512];
            }
        }

    float hreg[2][2][4];
#pragma unroll
    for (int mt = 0; mt < 2; mt++)
#pragma unroll
        for (int nt = 0; nt < 2; nt++)
#pragma unroll
            for (int rr = 0; rr < 4; rr++) hreg[mt][nt][rr] = 0.f;

    __syncthreads();    // BYs ready

    for (int p = 0; p < PATCHL; ++p) {
        // ---- 1. stage premix rows for this step's bytes (L2 -> LDS) ----
#pragma unroll
        for (int j = 0; j < 6; ++j) {
            const int idx = j * 512 + tid;          // uint4 index; 96 per row
            const int row = idx / 96, col = idx - row * 96;
            const int bv = p ? BYs[row * PATCHL + p - 1] : 0;
            *(uint4*)(PMs + row * PMS + col * 8) =
                *(const uint4*)(premixB + (size_t)bv * 768 + col * 8);
        }

        // ---- 2. coalesced hh write of h(p-1) (reads H, pre-overwrite) ----
        if (p) {
#pragma unroll
            for (int rj = 0; rj < 4; ++rj) {
                const int row = w * 4 + rj;
                const int boff = (lane * 8) ^ ((row & 7) << 4);   // un-swizzle
                const ushort4 v = *(const ushort4*)((const char*)(H + row * 256) + boff);
                *(ushort4*)(hh + ((size_t)(s0l + row) * PATCHL + (p - 1)) * 256 + lane * 4) = v;
            }
        }

        // ---- 3. recurrence: hg = h(p-1) @ W_hh^T ----
        f32x4 accr[2][2], accz[2][2], accn[2][2];
#pragma unroll
        for (int mt = 0; mt < 2; mt++)
#pragma unroll
            for (int nt = 0; nt < 2; nt++) {
                accr[mt][nt] = 0.f; accz[mt][nt] = 0.f; accn[mt][nt] = 0.f;
            }
        if (p != 0) {
#pragma unroll
            for (int ks = 0; ks < 8; ++ks) {
                bf16x8 a[2];
#pragma unroll
                for (int mt = 0; mt < 2; mt++) {
                    const int s = mt * 16 + l15;
                    const int off = (ks * 64 + kg * 16) ^ ((s & 7) << 4);
                    a[mt] = *(const bf16x8*)(H + s * 256 + (off >> 1));
                }
#pragma unroll
                for (int nt = 0; nt < 2; nt++) {
                    const int tb = w * 2 + nt;
                    const bf16x8 br = *(const bf16x8*)(wpack + (((size_t)(tb)      * 8 + ks) * 64 + lane) * 8);
                    const bf16x8 bz = *(const bf16x8*)(wpack + (((size_t)(16 + tb) * 8 + ks) * 64 + lane) * 8);
                    const bf16x8 bn = *(const bf16x8*)(wpack + (((size_t)(32 + tb) * 8 + ks) * 64 + lane) * 8);
#pragma unroll
                    for (int mt = 0; mt < 2; mt++) {
                        accr[mt][nt] = __builtin_amdgcn_mfma_f32_16x16x32_bf16(a[mt], br, accr[mt][nt], 0, 0, 0);
                        accz[mt][nt] = __builtin_amdgcn_mfma_f32_16x16x32_bf16(a[mt], bz, accz[mt][nt], 0, 0, 0);
                        accn[mt][nt] = __builtin_amdgcn_mfma_f32_16x16x32_bf16(a[mt], bn, accn[mt][nt], 0, 0, 0);
                    }
                }
            }
        }
        __syncthreads();   // PMs staged; all H reads (copy + MFMA) complete

        // ---- 5. gates + state update; write h(p) into H ----
#pragma unroll
        for (int mt = 0; mt < 2; mt++)
#pragma unroll
            for (int nt = 0; nt < 2; nt++) {
                const int u = w * 32 + nt * 16 + l15;
#pragma unroll
                for (int rr = 0; rr < 4; rr++) {
                    const int sl = mt * 16 + kg * 4 + rr;
                    const float xr = lgr[mt][nt][rr] + bf2f(PMs[sl * PMS + u]);
                    const float xz = lgz[mt][nt][rr] + bf2f(PMs[sl * PMS + 256 + u]);
                    const float xn = lgn[mt][nt][rr] + bf2f(PMs[sl * PMS + 512 + u]);
                    const float r = sigf(xr + accr[mt][nt][rr]);
                    const float z = sigf(xz + accz[mt][nt][rr]);
                    const float n = tanhf_(xn + r * (accn[mt][nt][rr] + bhn[nt]));
                    const float hn_ = (1.f - z) * n + z * hreg[mt][nt][rr];
                    hreg[mt][nt][rr] = hn_;
                    const int bo = (2 * u) ^ ((sl & 7) << 4);
                    H[sl * 256 + (bo >> 1)] = f2bf(hn_);
                }
            }
        __syncthreads();   // h(p) visible
    }

    // ---- final hh write for p = 15 ----
#pragma unroll
    for (int rj = 0; rj < 4; ++rj) {
        const int row = w * 4 + rj;
        const int boff = (lane * 8) ^ ((row & 7) << 4);
        const ushort4 v = *(const ushort4*)((const char*)(H + row * 256) + boff);
        *(ushort4*)(hh + ((size_t)(s0l + row) * PATCHL + (PATCHL - 1)) * 256 + lane * 4) = v;
    }
}

// ---------------------------------------------------------------------------
extern "C" void kernel_launch(void* const* d_in, const int* in_sizes, int n_in,
                              void* d_out, int out_size, void* d_ws, size_t ws_size,
                              hipStream_t stream)
{
    const float* latents = (const float*)d_in[0];   // [8192][1024]
    const int*   tb      = (const int*)d_in[1];     // [8192*16]
    const float* W_proj  = (const float*)d_in[2];   // [256][1024]
    const float* b_proj  = (const float*)d_in[3];   // [256]
    const float* emb     = (const float*)d_in[4];   // [256][256]
    const float* W_ih    = (const float*)d_in[5];   // [768][512]
    const float* W_hh    = (const float*)d_in[6];   // [768][256]
    const float* b_ih    = (const float*)d_in[7];   // [768]
    const float* b_hh    = (const float*)d_in[8];   // [768]
    const float* W_head  = (const float*)d_in[9];   // [256][256]
    const float* b_head  = (const float*)d_in[10];  // [256]
    float* out = (float*)d_out;

    // ---- workspace layout (bytes) ----
    char* w = (char*)d_ws;
    float* latg = (float*)w;                               w += (size_t)NSEQ * 768 * 4;     // 25.2 MB
    unsigned short* ctxb    = (unsigned short*)w;          w += (size_t)NSEQ * HIDN * 2;    // 4.2 MB
    unsigned short* premixB = (unsigned short*)w;          w += 256 * 768 * 2;
    unsigned short* bpack1  = (unsigned short*)w;          w += 16 * 32 * 64 * 8 * 2;
    unsigned short* bpack2  = (unsigned short*)w;          w += 48 * 8 * 64 * 8 * 2;
    unsigned short* bpack3  = (unsigned short*)w;          w += 48 * 8 * 64 * 8 * 2;
    unsigned short* wpackG  = (unsigned short*)w;          w += 48 * 8 * 64 * 8 * 2;        // gates
    unsigned short* bpackH  = (unsigned short*)w;          w += 16 * 8 * 64 * 8 * 2;        // head
    unsigned short* hh_c    = (unsigned short*)w;
    const size_t fixed_bytes = (size_t)(w - (char*)d_ws);
    const size_t chunk_full  = (size_t)NSEQ * PATCHL * 256 * 2;          // hh = 67 MB

    int nch = 1;
    while (nch < 16 && fixed_bytes + chunk_full / nch > ws_size) nch <<= 1;
    const int SPC = NSEQ / nch;                    // seqs per chunk

    // ---- weight packs (fragment-ordered bf16) ----
    hipLaunchKernelGGL(pack_frag, dim3(128), dim3(256), 0, stream, W_proj, 1024, 0, 32, bpack1);
    hipLaunchKernelGGL(pack_frag, dim3(96),  dim3(256), 0, stream, W_ih,   512, 256, 8, bpack2);
    hipLaunchKernelGGL(pack_frag, dim3(96),  dim3(256), 0, stream, W_ih,   512, 0,   8, bpack3);
    hipLaunchKernelGGL(pack_frag, dim3(96),  dim3(256), 0, stream, W_hh,   256, 0,   8, wpackG);
    hipLaunchKernelGGL(pack_frag, dim3(32),  dim3(256), 0, stream, W_head, 256, 0,   8, bpackH);

    // premixB(bf16) = emb @ W_ih[:,0:256]^T        [256][768]
    hipLaunchKernelGGL((gemm_mfma<false, true>), dim3(2, 12), dim3(512), 0, stream,
                       emb, 256, bpack3, 8, nullptr, premixB, 768, 256);
    // ctx(bf16) = latents @ W_proj^T + b_proj      [8192][256]
    hipLaunchKernelGGL((gemm_mfma<false, true>), dim3(NSEQ / 128, 4), dim3(512), 0, stream,
                       latents, 1024, bpack1, 32, b_proj, ctxb, 256, 1024);
    // latg(f32) = ctx @ W_ih[:,256:512]^T + b_ih   [8192][768]
    hipLaunchKernelGGL((gemm_mfma<true, false>), dim3(NSEQ / 128, 12), dim3(512), 0, stream,
                       ctxb, 256, bpack2, 8, b_ih, latg, 768, 256);

    // ---- per-chunk: fused scan -> head GEMM (stream-ordered) ----
    for (int c = 0; c < nch; ++c) {
        const int seq0 = c * SPC;
        hipLaunchKernelGGL(gru_scan_fused, dim3(SPC / 32), dim3(512), 0, stream,
                           tb, latg, premixB, wpackG, b_hh, hh_c, seq0);
        // logits = h_hist @ W_head^T + b_head    [SPC*16][256]
        hipLaunchKernelGGL((gemm_mfma<true, false>), dim3(SPC * PATCHL / 128, 4), dim3(512), 0, stream,
                           hh_c, 256, bpackH, 8, b_head,
                           out + (size_t)seq0 * PATCHL * VOCABN, 256, 256);
    }
}

// Round 8
// 408.594 us; speedup vs baseline: 1.6631x; 1.0013x over previous
//
#include <hip/hip_runtime.h>
#include <math.h>

// Problem constants
#define NSEQ 8192          // B*N
#define PATCHL 16
#define HIDN 256
#define VOCABN 256

typedef __attribute__((ext_vector_type(4))) float f32x4;
typedef __attribute__((ext_vector_type(8))) short bf16x8;   // 8 bf16 = 4 VGPRs

__device__ __forceinline__ unsigned short f2bf(float f) {
    unsigned int x = __float_as_uint(f);
    unsigned int r = (x + 0x7fffu + ((x >> 16) & 1u)) >> 16;
    return (unsigned short)r;
}
__device__ __forceinline__ float bf2f(unsigned short b) {
    return __uint_as_float(((unsigned int)b) << 16);
}
__device__ __forceinline__ float sigf(float x)   { return 1.f / (1.f + __expf(-x)); }
__device__ __forceinline__ float tanhf_(float x) { return 2.f / (1.f + __expf(-2.f * x)) - 1.f; }

// ---------------------------------------------------------------------------
// Fragment-order bf16 pack of a weight matrix slice (MFMA B operand).
// ---------------------------------------------------------------------------
__global__ __launch_bounds__(256)
void pack_frag(const float* __restrict__ src, int ld, int col0, int nks,
               unsigned short* __restrict__ dst)
{
    const int g = blockIdx.x * 256 + threadIdx.x;
    const int lane = g & 63;
    const int ks = (g / 64) % nks;
    const int T  = g / (64 * nks);
    const float* s = src + (size_t)(T * 16 + (lane & 15)) * ld + col0 + ks * 32 + ((lane >> 4) & 3) * 8;
    unsigned int q[4];
#pragma unroll
    for (int j = 0; j < 4; j++) {
        unsigned int lo = f2bf(s[2 * j]);
        unsigned int hi = f2bf(s[2 * j + 1]);
        q[j] = lo | (hi << 16);
    }
    uint4 v; v.x = q[0]; v.y = q[1]; v.z = q[2]; v.w = q[3];
    *(uint4*)(dst + (size_t)g * 8) = v;
}

// ---------------------------------------------------------------------------
// bf16 MFMA GEMM: C[m][n] = sum_k A[m][k] * W[n][k] (+bias[n])
// BM=128 BN=64 BK=64, 512 threads (8 waves). Verified rounds 3-7.
// ---------------------------------------------------------------------------
template<bool ASRC_BF16, bool OUT_BF16>
__global__ __launch_bounds__(512)
void gemm_mfma(const void* __restrict__ Asrc, int lda,
               const unsigned short* __restrict__ bpack, int nks_total,
               const float* __restrict__ bias, void* __restrict__ Cdst, int ldc,
               int K)
{
    const int tid = threadIdx.x;
    const int w = tid >> 6, lane = tid & 63;
    const int l15 = lane & 15, kg = (lane >> 4) & 3;
    const int bm = blockIdx.x * 128, bn = blockIdx.y * 64;

    __shared__ unsigned short As[2][128 * 64];

    const int srow = tid >> 2;           // 0..127
    const int scol = (tid & 3) * 16;     // 0,16,32,48
    const int nkt = K / 64;

    f32x4 acc[4];
#pragma unroll
    for (int nt = 0; nt < 4; nt++) acc[nt] = 0.f;

    const int wb0 = srow * 128 + ((scol * 2) ^ ((srow & 7) << 4));
    const int wb1 = srow * 128 + ((scol * 2 + 16) ^ ((srow & 7) << 4));

#define STAGE(kt, buf) do {                                                         \
        const int gk = (kt) * 64 + scol;                                            \
        unsigned short tmp[16];                                                     \
        if (ASRC_BF16) {                                                            \
            const unsigned short* A = (const unsigned short*)Asrc;                  \
            *(uint4*)(tmp)     = *(const uint4*)(A + (size_t)(bm + srow) * lda + gk);      \
            *(uint4*)(tmp + 8) = *(const uint4*)(A + (size_t)(bm + srow) * lda + gk + 8);  \
        } else {                                                                    \
            const float* A = (const float*)Asrc;                                    \
            const float4 a0 = *(const float4*)(A + (size_t)(bm + srow) * lda + gk);       \
            const float4 a1 = *(const float4*)(A + (size_t)(bm + srow) * lda + gk + 4);   \
            const float4 a2 = *(const float4*)(A + (size_t)(bm + srow) * lda + gk + 8);   \
            const float4 a3 = *(const float4*)(A + (size_t)(bm + srow) * lda + gk + 12);  \
            tmp[0] = f2bf(a0.x);  tmp[1] = f2bf(a0.y);  tmp[2] = f2bf(a0.z);  tmp[3] = f2bf(a0.w);   \
            tmp[4] = f2bf(a1.x);  tmp[5] = f2bf(a1.y);  tmp[6] = f2bf(a1.z);  tmp[7] = f2bf(a1.w);   \
            tmp[8] = f2bf(a2.x);  tmp[9] = f2bf(a2.y);  tmp[10] = f2bf(a2.z); tmp[11] = f2bf(a2.w);  \
            tmp[12] = f2bf(a3.x); tmp[13] = f2bf(a3.y); tmp[14] = f2bf(a3.z); tmp[15] = f2bf(a3.w);  \
        }                                                                           \
        *(uint4*)((char*)As[buf] + wb0) = *(uint4*)tmp;                             \
        *(uint4*)((char*)As[buf] + wb1) = *(uint4*)(tmp + 8);                       \
    } while (0)

    STAGE(0, 0);
    __syncthreads();

    for (int kt = 0; kt < nkt; ++kt) {
        if (kt + 1 < nkt) STAGE(kt + 1, (kt + 1) & 1);
        const unsigned short* buf = As[kt & 1];
        const int row = w * 16 + l15;
#pragma unroll
        for (int ks = 0; ks < 2; ++ks) {
            const int bo = row * 128 + (((ks * 64) + kg * 16) ^ ((row & 7) << 4));
            const bf16x8 a = *(const bf16x8*)((const char*)buf + bo);
#pragma unroll
            for (int nt = 0; nt < 4; ++nt) {
                const int T = blockIdx.y * 4 + nt;
                const bf16x8 b = *(const bf16x8*)(bpack + (((size_t)T * nks_total + (kt * 2 + ks)) * 64 + lane) * 8);
                acc[nt] = __builtin_amdgcn_mfma_f32_16x16x32_bf16(a, b, acc[nt], 0, 0, 0);
            }
        }
        __syncthreads();
    }
#undef STAGE

#pragma unroll
    for (int nt = 0; nt < 4; ++nt) {
        const int n = bn + nt * 16 + l15;
        const float bv = bias ? bias[n] : 0.f;
#pragma unroll
        for (int rr = 0; rr < 4; ++rr) {
            const int m = bm + w * 16 + kg * 4 + rr;
            const float v = acc[nt][rr] + bv;
            if (OUT_BF16) ((unsigned short*)Cdst)[(size_t)m * ldc + n] = f2bf(v);
            else          ((float*)Cdst)[(size_t)m * ldc + n] = v;
        }
    }
}

// ---------------------------------------------------------------------------
// Fused GRU scan. 32 seqs/block, 512 threads, 1 block/CU.
// __launch_bounds__(512, 2): min 2 waves/EU == exactly our 1-block/CU
// occupancy -> 256-VGPR cap. r7's bare (512) let the allocator target the
// 128-VGPR/16-wave bucket and spill ~140 MB of scratch per dispatch
// (FETCH 172 MB vs ~30 MB algorithmic); grid >= 256 blocks means >1 block/CU
// never happens, so the extra occupancy was unreachable anyway.
// ---------------------------------------------------------------------------
#define PMS 776   // padded row stride (shorts)
__global__ __launch_bounds__(512, 2)
void gru_scan_fused(const int* __restrict__ bytes,         // [NSEQ*16]
                    const float* __restrict__ latg,        // [NSEQ][768] (incl b_ih)
                    const unsigned short* __restrict__ premixB, // [256][768] bf16
                    const unsigned short* __restrict__ wpack,   // 48 gate tiles
                    const float* __restrict__ b_hh,        // [768]
                    unsigned short* __restrict__ hh,       // [SPC*16][256] bf16
                    int seq0)
{
    const int tid  = threadIdx.x;
    const int w    = tid >> 6;
    const int lane = tid & 63;
    const int l15  = lane & 15;
    const int kg   = (lane >> 4) & 3;
    const int s0l  = blockIdx.x * 32;            // chunk-local
    const int s0g  = seq0 + s0l;                 // global

    __shared__ unsigned short PMs[32 * PMS];     // 49.7 KB
    __shared__ unsigned short H[32 * 256];       // 16 KB
    __shared__ int BYs[512];                     // 2 KB

    BYs[tid] = bytes[(size_t)s0g * PATCHL + tid];

    float bhr[2], bhz[2], bhn[2];
#pragma unroll
    for (int nt = 0; nt < 2; nt++) {
        const int u = w * 32 + nt * 16 + l15;
        bhr[nt] = b_hh[u]; bhz[nt] = b_hh[256 + u]; bhn[nt] = b_hh[512 + u];
    }

    // step-invariant gate pre-activations -> registers (recurrent bias folded
    // into r,z; n keeps bhn separate since n = tanh(xn + r*(accn+bhn)))
    float lgr[2][2][4], lgz[2][2][4], lgn[2][2][4];
#pragma unroll
    for (int mt = 0; mt < 2; mt++)
#pragma unroll
        for (int nt = 0; nt < 2; nt++) {
            const int u = w * 32 + nt * 16 + l15;
#pragma unroll
            for (int rr = 0; rr < 4; rr++) {
                const int sg = s0g + mt * 16 + kg * 4 + rr;
                const float* lg = latg + (size_t)sg * 768;
                lgr[mt][nt][rr] = lg[u]       + bhr[nt];
                lgz[mt][nt][rr] = lg[u + 256] + bhz[nt];
                lgn[mt][nt][rr] = lg[u + 512];
            }
        }

    float hreg[2][2][4];
#pragma unroll
    for (int mt = 0; mt < 2; mt++)
#pragma unroll
        for (int nt = 0; nt < 2; nt++)
#pragma unroll
            for (int rr = 0; rr < 4; rr++) hreg[mt][nt][rr] = 0.f;

    __syncthreads();    // BYs ready

    for (int p = 0; p < PATCHL; ++p) {
        // ---- 1. stage premix rows for this step's bytes (L2 -> LDS) ----
#pragma unroll
        for (int j = 0; j < 6; ++j) {
            const int idx = j * 512 + tid;          // uint4 index; 96 per row
            const int row = idx / 96, col = idx - row * 96;
            const int bv = p ? BYs[row * PATCHL + p - 1] : 0;
            *(uint4*)(PMs + row * PMS + col * 8) =
                *(const uint4*)(premixB + (size_t)bv * 768 + col * 8);
        }

        // ---- 2. coalesced hh write of h(p-1) (reads H, pre-overwrite) ----
        if (p) {
#pragma unroll
            for (int rj = 0; rj < 4; ++rj) {
                const int row = w * 4 + rj;
                const int boff = (lane * 8) ^ ((row & 7) << 4);   // un-swizzle
                const ushort4 v = *(const ushort4*)((const char*)(H + row * 256) + boff);
                *(ushort4*)(hh + ((size_t)(s0l + row) * PATCHL + (p - 1)) * 256 + lane * 4) = v;
            }
        }

        // ---- 3. recurrence: hg = h(p-1) @ W_hh^T ----
        f32x4 accr[2][2], accz[2][2], accn[2][2];
#pragma unroll
        for (int mt = 0; mt < 2; mt++)
#pragma unroll
            for (int nt = 0; nt < 2; nt++) {
                accr[mt][nt] = 0.f; accz[mt][nt] = 0.f; accn[mt][nt] = 0.f;
            }
        if (p != 0) {
#pragma unroll
            for (int ks = 0; ks < 8; ++ks) {
                bf16x8 a[2];
#pragma unroll
                for (int mt = 0; mt < 2; mt++) {
                    const int s = mt * 16 + l15;
                    const int off = (ks * 64 + kg * 16) ^ ((s & 7) << 4);
                    a[mt] = *(const bf16x8*)(H + s * 256 + (off >> 1));
                }
#pragma unroll
                for (int nt = 0; nt < 2; nt++) {
                    const int tb = w * 2 + nt;
                    const bf16x8 br = *(const bf16x8*)(wpack + (((size_t)(tb)      * 8 + ks) * 64 + lane) * 8);
                    const bf16x8 bz = *(const bf16x8*)(wpack + (((size_t)(16 + tb) * 8 + ks) * 64 + lane) * 8);
                    const bf16x8 bn = *(const bf16x8*)(wpack + (((size_t)(32 + tb) * 8 + ks) * 64 + lane) * 8);
#pragma unroll
                    for (int mt = 0; mt < 2; mt++) {
                        accr[mt][nt] = __builtin_amdgcn_mfma_f32_16x16x32_bf16(a[mt], br, accr[mt][nt], 0, 0, 0);
                        accz[mt][nt] = __builtin_amdgcn_mfma_f32_16x16x32_bf16(a[mt], bz, accz[mt][nt], 0, 0, 0);
                        accn[mt][nt] = __builtin_amdgcn_mfma_f32_16x16x32_bf16(a[mt], bn, accn[mt][nt], 0, 0, 0);
                    }
                }
            }
        }
        __syncthreads();   // PMs staged; all H reads (copy + MFMA) complete

        // ---- 5. gates + state update; write h(p) into H ----
#pragma unroll
        for (int mt = 0; mt < 2; mt++)
#pragma unroll
            for (int nt = 0; nt < 2; nt++) {
                const int u = w * 32 + nt * 16 + l15;
#pragma unroll
                for (int rr = 0; rr < 4; rr++) {
                    const int sl = mt * 16 + kg * 4 + rr;
                    const float xr = lgr[mt][nt][rr] + bf2f(PMs[sl * PMS + u]);
                    const float xz = lgz[mt][nt][rr] + bf2f(PMs[sl * PMS + 256 + u]);
                    const float xn = lgn[mt][nt][rr] + bf2f(PMs[sl * PMS + 512 + u]);
                    const float r = sigf(xr + accr[mt][nt][rr]);
                    const float z = sigf(xz + accz[mt][nt][rr]);
                    const float n = tanhf_(xn + r * (accn[mt][nt][rr] + bhn[nt]));
                    const float hn_ = (1.f - z) * n + z * hreg[mt][nt][rr];
                    hreg[mt][nt][rr] = hn_;
                    const int bo = (2 * u) ^ ((sl & 7) << 4);
                    H[sl * 256 + (bo >> 1)] = f2bf(hn_);
                }
            }
        __syncthreads();   // h(p) visible
    }

    // ---- final hh write for p = 15 ----
#pragma unroll
    for (int rj = 0; rj < 4; ++rj) {
        const int row = w * 4 + rj;
        const int boff = (lane * 8) ^ ((row & 7) << 4);
        const ushort4 v = *(const ushort4*)((const char*)(H + row * 256) + boff);
        *(ushort4*)(hh + ((size_t)(s0l + row) * PATCHL + (PATCHL - 1)) * 256 + lane * 4) = v;
    }
}

// ---------------------------------------------------------------------------
extern "C" void kernel_launch(void* const* d_in, const int* in_sizes, int n_in,
                              void* d_out, int out_size, void* d_ws, size_t ws_size,
                              hipStream_t stream)
{
    const float* latents = (const float*)d_in[0];   // [8192][1024]
    const int*   tb      = (const int*)d_in[1];     // [8192*16]
    const float* W_proj  = (const float*)d_in[2];   // [256][1024]
    const float* b_proj  = (const float*)d_in[3];   // [256]
    const float* emb     = (const float*)d_in[4];   // [256][256]
    const float* W_ih    = (const float*)d_in[5];   // [768][512]
    const float* W_hh    = (const float*)d_in[6];   // [768][256]
    const float* b_ih    = (const float*)d_in[7];   // [768]
    const float* b_hh    = (const float*)d_in[8];   // [768]
    const float* W_head  = (const float*)d_in[9];   // [256][256]
    const float* b_head  = (const float*)d_in[10];  // [256]
    float* out = (float*)d_out;

    // ---- workspace layout (bytes) ----
    char* w = (char*)d_ws;
    float* latg = (float*)w;                               w += (size_t)NSEQ * 768 * 4;     // 25.2 MB
    unsigned short* ctxb    = (unsigned short*)w;          w += (size_t)NSEQ * HIDN * 2;    // 4.2 MB
    unsigned short* premixB = (unsigned short*)w;          w += 256 * 768 * 2;
    unsigned short* bpack1  = (unsigned short*)w;          w += 16 * 32 * 64 * 8 * 2;
    unsigned short* bpack2  = (unsigned short*)w;          w += 48 * 8 * 64 * 8 * 2;
    unsigned short* bpack3  = (unsigned short*)w;          w += 48 * 8 * 64 * 8 * 2;
    unsigned short* wpackG  = (unsigned short*)w;          w += 48 * 8 * 64 * 8 * 2;        // gates
    unsigned short* bpackH  = (unsigned short*)w;          w += 16 * 8 * 64 * 8 * 2;        // head
    unsigned short* hh_c    = (unsigned short*)w;
    const size_t fixed_bytes = (size_t)(w - (char*)d_ws);
    const size_t chunk_full  = (size_t)NSEQ * PATCHL * 256 * 2;          // hh = 67 MB

    int nch = 1;
    while (nch < 16 && fixed_bytes + chunk_full / nch > ws_size) nch <<= 1;
    const int SPC = NSEQ / nch;                    // seqs per chunk

    // ---- weight packs (fragment-ordered bf16) ----
    hipLaunchKernelGGL(pack_frag, dim3(128), dim3(256), 0, stream, W_proj, 1024, 0, 32, bpack1);
    hipLaunchKernelGGL(pack_frag, dim3(96),  dim3(256), 0, stream, W_ih,   512, 256, 8, bpack2);
    hipLaunchKernelGGL(pack_frag, dim3(96),  dim3(256), 0, stream, W_ih,   512, 0,   8, bpack3);
    hipLaunchKernelGGL(pack_frag, dim3(96),  dim3(256), 0, stream, W_hh,   256, 0,   8, wpackG);
    hipLaunchKernelGGL(pack_frag, dim3(32),  dim3(256), 0, stream, W_head, 256, 0,   8, bpackH);

    // premixB(bf16) = emb @ W_ih[:,0:256]^T        [256][768]
    hipLaunchKernelGGL((gemm_mfma<false, true>), dim3(2, 12), dim3(512), 0, stream,
                       emb, 256, bpack3, 8, nullptr, premixB, 768, 256);
    // ctx(bf16) = latents @ W_proj^T + b_proj      [8192][256]
    hipLaunchKernelGGL((gemm_mfma<false, true>), dim3(NSEQ / 128, 4), dim3(512), 0, stream,
                       latents, 1024, bpack1, 32, b_proj, ctxb, 256, 1024);
    // latg(f32) = ctx @ W_ih[:,256:512]^T + b_ih   [8192][768]
    hipLaunchKernelGGL((gemm_mfma<true, false>), dim3(NSEQ / 128, 12), dim3(512), 0, stream,
                       ctxb, 256, bpack2, 8, b_ih, latg, 768, 256);

    // ---- per-chunk: fused scan -> head GEMM (stream-ordered) ----
    for (int c = 0; c < nch; ++c) {
        const int seq0 = c * SPC;
        hipLaunchKernelGGL(gru_scan_fused, dim3(SPC / 32), dim3(512), 0, stream,
                           tb, latg, premixB, wpackG, b_hh, hh_c, seq0);
        // logits = h_hist @ W_head^T + b_head    [SPC*16][256]
        hipLaunchKernelGGL((gemm_mfma<true, false>), dim3(SPC * PATCHL / 128, 4), dim3(512), 0, stream,
                           hh_c, 256, bpackH, 8, b_head,
                           out + (size_t)seq0 * PATCHL * VOCABN, 256, 256);
    }
}

// Round 9
// 407.096 us; speedup vs baseline: 1.6692x; 1.0037x over previous
//
#include <hip/hip_runtime.h>
#include <math.h>

// Problem constants
#define NSEQ 8192          // B*N
#define PATCHL 16
#define HIDN 256
#define VOCABN 256

typedef __attribute__((ext_vector_type(4))) float f32x4;
typedef __attribute__((ext_vector_type(8))) short bf16x8;   // 8 bf16 = 4 VGPRs

__device__ __forceinline__ unsigned short f2bf(float f) {
    unsigned int x = __float_as_uint(f);
    unsigned int r = (x + 0x7fffu + ((x >> 16) & 1u)) >> 16;
    return (unsigned short)r;
}
__device__ __forceinline__ float bf2f(unsigned short b) {
    return __uint_as_float(((unsigned int)b) << 16);
}
__device__ __forceinline__ float sigf(float x)   { return 1.f / (1.f + __expf(-x)); }
__device__ __forceinline__ float tanhf_(float x) { return 2.f / (1.f + __expf(-2.f * x)) - 1.f; }

// ---------------------------------------------------------------------------
// Fragment-order bf16 pack of a weight matrix slice (MFMA B operand).
// ---------------------------------------------------------------------------
__global__ __launch_bounds__(256)
void pack_frag(const float* __restrict__ src, int ld, int col0, int nks,
               unsigned short* __restrict__ dst)
{
    const int g = blockIdx.x * 256 + threadIdx.x;
    const int lane = g & 63;
    const int ks = (g / 64) % nks;
    const int T  = g / (64 * nks);
    const float* s = src + (size_t)(T * 16 + (lane & 15)) * ld + col0 + ks * 32 + ((lane >> 4) & 3) * 8;
    unsigned int q[4];
#pragma unroll
    for (int j = 0; j < 4; j++) {
        unsigned int lo = f2bf(s[2 * j]);
        unsigned int hi = f2bf(s[2 * j + 1]);
        q[j] = lo | (hi << 16);
    }
    uint4 v; v.x = q[0]; v.y = q[1]; v.z = q[2]; v.w = q[3];
    *(uint4*)(dst + (size_t)g * 8) = v;
}

// ---------------------------------------------------------------------------
// bf16 MFMA GEMM: C[m][n] = sum_k A[m][k] * W[n][k] (+bias[n])
// BM=128 BN=64 BK=64, 512 threads (8 waves). Verified rounds 3-8.
// ---------------------------------------------------------------------------
template<bool ASRC_BF16, bool OUT_BF16>
__global__ __launch_bounds__(512)
void gemm_mfma(const void* __restrict__ Asrc, int lda,
               const unsigned short* __restrict__ bpack, int nks_total,
               const float* __restrict__ bias, void* __restrict__ Cdst, int ldc,
               int K)
{
    const int tid = threadIdx.x;
    const int w = tid >> 6, lane = tid & 63;
    const int l15 = lane & 15, kg = (lane >> 4) & 3;
    const int bm = blockIdx.x * 128, bn = blockIdx.y * 64;

    __shared__ unsigned short As[2][128 * 64];

    const int srow = tid >> 2;           // 0..127
    const int scol = (tid & 3) * 16;     // 0,16,32,48
    const int nkt = K / 64;

    f32x4 acc[4];
#pragma unroll
    for (int nt = 0; nt < 4; nt++) acc[nt] = 0.f;

    const int wb0 = srow * 128 + ((scol * 2) ^ ((srow & 7) << 4));
    const int wb1 = srow * 128 + ((scol * 2 + 16) ^ ((srow & 7) << 4));

#define STAGE(kt, buf) do {                                                         \
        const int gk = (kt) * 64 + scol;                                            \
        unsigned short tmp[16];                                                     \
        if (ASRC_BF16) {                                                            \
            const unsigned short* A = (const unsigned short*)Asrc;                  \
            *(uint4*)(tmp)     = *(const uint4*)(A + (size_t)(bm + srow) * lda + gk);      \
            *(uint4*)(tmp + 8) = *(const uint4*)(A + (size_t)(bm + srow) * lda + gk + 8);  \
        } else {                                                                    \
            const float* A = (const float*)Asrc;                                    \
            const float4 a0 = *(const float4*)(A + (size_t)(bm + srow) * lda + gk);       \
            const float4 a1 = *(const float4*)(A + (size_t)(bm + srow) * lda + gk + 4);   \
            const float4 a2 = *(const float4*)(A + (size_t)(bm + srow) * lda + gk + 8);   \
            const float4 a3 = *(const float4*)(A + (size_t)(bm + srow) * lda + gk + 12);  \
            tmp[0] = f2bf(a0.x);  tmp[1] = f2bf(a0.y);  tmp[2] = f2bf(a0.z);  tmp[3] = f2bf(a0.w);   \
            tmp[4] = f2bf(a1.x);  tmp[5] = f2bf(a1.y);  tmp[6] = f2bf(a1.z);  tmp[7] = f2bf(a1.w);   \
            tmp[8] = f2bf(a2.x);  tmp[9] = f2bf(a2.y);  tmp[10] = f2bf(a2.z); tmp[11] = f2bf(a2.w);  \
            tmp[12] = f2bf(a3.x); tmp[13] = f2bf(a3.y); tmp[14] = f2bf(a3.z); tmp[15] = f2bf(a3.w);  \
        }                                                                           \
        *(uint4*)((char*)As[buf] + wb0) = *(uint4*)tmp;                             \
        *(uint4*)((char*)As[buf] + wb1) = *(uint4*)(tmp + 8);                       \
    } while (0)

    STAGE(0, 0);
    __syncthreads();

    for (int kt = 0; kt < nkt; ++kt) {
        if (kt + 1 < nkt) STAGE(kt + 1, (kt + 1) & 1);
        const unsigned short* buf = As[kt & 1];
        const int row = w * 16 + l15;
#pragma unroll
        for (int ks = 0; ks < 2; ++ks) {
            const int bo = row * 128 + (((ks * 64) + kg * 16) ^ ((row & 7) << 4));
            const bf16x8 a = *(const bf16x8*)((const char*)buf + bo);
#pragma unroll
            for (int nt = 0; nt < 4; ++nt) {
                const int T = blockIdx.y * 4 + nt;
                const bf16x8 b = *(const bf16x8*)(bpack + (((size_t)T * nks_total + (kt * 2 + ks)) * 64 + lane) * 8);
                acc[nt] = __builtin_amdgcn_mfma_f32_16x16x32_bf16(a, b, acc[nt], 0, 0, 0);
            }
        }
        __syncthreads();
    }
#undef STAGE

#pragma unroll
    for (int nt = 0; nt < 4; ++nt) {
        const int n = bn + nt * 16 + l15;
        const float bv = bias ? bias[n] : 0.f;
#pragma unroll
        for (int rr = 0; rr < 4; ++rr) {
            const int m = bm + w * 16 + kg * 4 + rr;
            const float v = acc[nt][rr] + bv;
            if (OUT_BF16) ((unsigned short*)Cdst)[(size_t)m * ldc + n] = f2bf(v);
            else          ((float*)Cdst)[(size_t)m * ldc + n] = v;
        }
    }
}

// ---------------------------------------------------------------------------
// Fused GRU scan. 32 seqs/block, 512 threads, 1 block/CU.
// __launch_bounds__(512, 1): observed hipcc mapping on this target is
// VGPR cap = 2048/(8*N) (N=4 -> 64, N=2 -> 128, both spilled ~140-700 MB of
// scratch). N=1 -> 256-VGPR bucket; ~180-reg payload fits with zero spill.
// Grid >= 256 blocks = 1 block/CU either way, so no occupancy is sacrificed.
// ---------------------------------------------------------------------------
#define PMS 776   // padded row stride (shorts)
__global__ __launch_bounds__(512, 1)
void gru_scan_fused(const int* __restrict__ bytes,         // [NSEQ*16]
                    const float* __restrict__ latg,        // [NSEQ][768] (incl b_ih)
                    const unsigned short* __restrict__ premixB, // [256][768] bf16
                    const unsigned short* __restrict__ wpack,   // 48 gate tiles
                    const float* __restrict__ b_hh,        // [768]
                    unsigned short* __restrict__ hh,       // [SPC*16][256] bf16
                    int seq0)
{
    const int tid  = threadIdx.x;
    const int w    = tid >> 6;
    const int lane = tid & 63;
    const int l15  = lane & 15;
    const int kg   = (lane >> 4) & 3;
    const int s0l  = blockIdx.x * 32;            // chunk-local
    const int s0g  = seq0 + s0l;                 // global

    __shared__ unsigned short PMs[32 * PMS];     // 49.7 KB
    __shared__ unsigned short H[32 * 256];       // 16 KB
    __shared__ int BYs[512];                     // 2 KB

    BYs[tid] = bytes[(size_t)s0g * PATCHL + tid];

    float bhr[2], bhz[2], bhn[2];
#pragma unroll
    for (int nt = 0; nt < 2; nt++) {
        const int u = w * 32 + nt * 16 + l15;
        bhr[nt] = b_hh[u]; bhz[nt] = b_hh[256 + u]; bhn[nt] = b_hh[512 + u];
    }

    // step-invariant gate pre-activations -> registers (recurrent bias folded
    // into r,z; n keeps bhn separate since n = tanh(xn + r*(accn+bhn)))
    float lgr[2][2][4], lgz[2][2][4], lgn[2][2][4];
#pragma unroll
    for (int mt = 0; mt < 2; mt++)
#pragma unroll
        for (int nt = 0; nt < 2; nt++) {
            const int u = w * 32 + nt * 16 + l15;
#pragma unroll
            for (int rr = 0; rr < 4; rr++) {
                const int sg = s0g + mt * 16 + kg * 4 + rr;
                const float* lg = latg + (size_t)sg * 768;
                lgr[mt][nt][rr] = lg[u]       + bhr[nt];
                lgz[mt][nt][rr] = lg[u + 256] + bhz[nt];
                lgn[mt][nt][rr] = lg[u + 512];
            }
        }

    float hreg[2][2][4];
#pragma unroll
    for (int mt = 0; mt < 2; mt++)
#pragma unroll
        for (int nt = 0; nt < 2; nt++)
#pragma unroll
            for (int rr = 0; rr < 4; rr++) hreg[mt][nt][rr] = 0.f;

    __syncthreads();    // BYs ready

    for (int p = 0; p < PATCHL; ++p) {
        // ---- 1. stage premix rows for this step's bytes (L2 -> LDS) ----
#pragma unroll
        for (int j = 0; j < 6; ++j) {
            const int idx = j * 512 + tid;          // uint4 index; 96 per row
            const int row = idx / 96, col = idx - row * 96;
            const int bv = p ? BYs[row * PATCHL + p - 1] : 0;
            *(uint4*)(PMs + row * PMS + col * 8) =
                *(const uint4*)(premixB + (size_t)bv * 768 + col * 8);
        }

        // ---- 2. coalesced hh write of h(p-1) (reads H, pre-overwrite) ----
        if (p) {
#pragma unroll
            for (int rj = 0; rj < 4; ++rj) {
                const int row = w * 4 + rj;
                const int boff = (lane * 8) ^ ((row & 7) << 4);   // un-swizzle
                const ushort4 v = *(const ushort4*)((const char*)(H + row * 256) + boff);
                *(ushort4*)(hh + ((size_t)(s0l + row) * PATCHL + (p - 1)) * 256 + lane * 4) = v;
            }
        }

        // ---- 3. recurrence: hg = h(p-1) @ W_hh^T ----
        f32x4 accr[2][2], accz[2][2], accn[2][2];
#pragma unroll
        for (int mt = 0; mt < 2; mt++)
#pragma unroll
            for (int nt = 0; nt < 2; nt++) {
                accr[mt][nt] = 0.f; accz[mt][nt] = 0.f; accn[mt][nt] = 0.f;
            }
        if (p != 0) {
#pragma unroll
            for (int ks = 0; ks < 8; ++ks) {
                bf16x8 a[2];
#pragma unroll
                for (int mt = 0; mt < 2; mt++) {
                    const int s = mt * 16 + l15;
                    const int off = (ks * 64 + kg * 16) ^ ((s & 7) << 4);
                    a[mt] = *(const bf16x8*)(H + s * 256 + (off >> 1));
                }
#pragma unroll
                for (int nt = 0; nt < 2; nt++) {
                    const int tb = w * 2 + nt;
                    const bf16x8 br = *(const bf16x8*)(wpack + (((size_t)(tb)      * 8 + ks) * 64 + lane) * 8);
                    const bf16x8 bz = *(const bf16x8*)(wpack + (((size_t)(16 + tb) * 8 + ks) * 64 + lane) * 8);
                    const bf16x8 bn = *(const bf16x8*)(wpack + (((size_t)(32 + tb) * 8 + ks) * 64 + lane) * 8);
#pragma unroll
                    for (int mt = 0; mt < 2; mt++) {
                        accr[mt][nt] = __builtin_amdgcn_mfma_f32_16x16x32_bf16(a[mt], br, accr[mt][nt], 0, 0, 0);
                        accz[mt][nt] = __builtin_amdgcn_mfma_f32_16x16x32_bf16(a[mt], bz, accz[mt][nt], 0, 0, 0);
                        accn[mt][nt] = __builtin_amdgcn_mfma_f32_16x16x32_bf16(a[mt], bn, accn[mt][nt], 0, 0, 0);
                    }
                }
            }
        }
        __syncthreads();   // PMs staged; all H reads (copy + MFMA) complete

        // ---- 5. gates + state update; write h(p) into H ----
#pragma unroll
        for (int mt = 0; mt < 2; mt++)
#pragma unroll
            for (int nt = 0; nt < 2; nt++) {
                const int u = w * 32 + nt * 16 + l15;
#pragma unroll
                for (int rr = 0; rr < 4; rr++) {
                    const int sl = mt * 16 + kg * 4 + rr;
                    const float xr = lgr[mt][nt][rr] + bf2f(PMs[sl * PMS + u]);
                    const float xz = lgz[mt][nt][rr] + bf2f(PMs[sl * PMS + 256 + u]);
                    const float xn = lgn[mt][nt][rr] + bf2f(PMs[sl * PMS + 512 + u]);
                    const float r = sigf(xr + accr[mt][nt][rr]);
                    const float z = sigf(xz + accz[mt][nt][rr]);
                    const float n = tanhf_(xn + r * (accn[mt][nt][rr] + bhn[nt]));
                    const float hn_ = (1.f - z) * n + z * hreg[mt][nt][rr];
                    hreg[mt][nt][rr] = hn_;
                    const int bo = (2 * u) ^ ((sl & 7) << 4);
                    H[sl * 256 + (bo >> 1)] = f2bf(hn_);
                }
            }
        __syncthreads();   // h(p) visible
    }

    // ---- final hh write for p = 15 ----
#pragma unroll
    for (int rj = 0; rj < 4; ++rj) {
        const int row = w * 4 + rj;
        const int boff = (lane * 8) ^ ((row & 7) << 4);
        const ushort4 v = *(const ushort4*)((const char*)(H + row * 256) + boff);
        *(ushort4*)(hh + ((size_t)(s0l + row) * PATCHL + (PATCHL - 1)) * 256 + lane * 4) = v;
    }
}

// ---------------------------------------------------------------------------
extern "C" void kernel_launch(void* const* d_in, const int* in_sizes, int n_in,
                              void* d_out, int out_size, void* d_ws, size_t ws_size,
                              hipStream_t stream)
{
    const float* latents = (const float*)d_in[0];   // [8192][1024]
    const int*   tb      = (const int*)d_in[1];     // [8192*16]
    const float* W_proj  = (const float*)d_in[2];   // [256][1024]
    const float* b_proj  = (const float*)d_in[3];   // [256]
    const float* emb     = (const float*)d_in[4];   // [256][256]
    const float* W_ih    = (const float*)d_in[5];   // [768][512]
    const float* W_hh    = (const float*)d_in[6];   // [768][256]
    const float* b_ih    = (const float*)d_in[7];   // [768]
    const float* b_hh    = (const float*)d_in[8];   // [768]
    const float* W_head  = (const float*)d_in[9];   // [256][256]
    const float* b_head  = (const float*)d_in[10];  // [256]
    float* out = (float*)d_out;

    // ---- workspace layout (bytes) ----
    char* w = (char*)d_ws;
    float* latg = (float*)w;                               w += (size_t)NSEQ * 768 * 4;     // 25.2 MB
    unsigned short* ctxb    = (unsigned short*)w;          w += (size_t)NSEQ * HIDN * 2;    // 4.2 MB
    unsigned short* premixB = (unsigned short*)w;          w += 256 * 768 * 2;
    unsigned short* bpack1  = (unsigned short*)w;          w += 16 * 32 * 64 * 8 * 2;
    unsigned short* bpack2  = (unsigned short*)w;          w += 48 * 8 * 64 * 8 * 2;
    unsigned short* bpack3  = (unsigned short*)w;          w += 48 * 8 * 64 * 8 * 2;
    unsigned short* wpackG  = (unsigned short*)w;          w += 48 * 8 * 64 * 8 * 2;        // gates
    unsigned short* bpackH  = (unsigned short*)w;          w += 16 * 8 * 64 * 8 * 2;        // head
    unsigned short* hh_c    = (unsigned short*)w;
    const size_t fixed_bytes = (size_t)(w - (char*)d_ws);
    const size_t chunk_full  = (size_t)NSEQ * PATCHL * 256 * 2;          // hh = 67 MB

    int nch = 1;
    while (nch < 16 && fixed_bytes + chunk_full / nch > ws_size) nch <<= 1;
    const int SPC = NSEQ / nch;                    // seqs per chunk

    // ---- weight packs (fragment-ordered bf16) ----
    hipLaunchKernelGGL(pack_frag, dim3(128), dim3(256), 0, stream, W_proj, 1024, 0, 32, bpack1);
    hipLaunchKernelGGL(pack_frag, dim3(96),  dim3(256), 0, stream, W_ih,   512, 256, 8, bpack2);
    hipLaunchKernelGGL(pack_frag, dim3(96),  dim3(256), 0, stream, W_ih,   512, 0,   8, bpack3);
    hipLaunchKernelGGL(pack_frag, dim3(96),  dim3(256), 0, stream, W_hh,   256, 0,   8, wpackG);
    hipLaunchKernelGGL(pack_frag, dim3(32),  dim3(256), 0, stream, W_head, 256, 0,   8, bpackH);

    // premixB(bf16) = emb @ W_ih[:,0:256]^T        [256][768]
    hipLaunchKernelGGL((gemm_mfma<false, true>), dim3(2, 12), dim3(512), 0, stream,
                       emb, 256, bpack3, 8, nullptr, premixB, 768, 256);
    // ctx(bf16) = latents @ W_proj^T + b_proj      [8192][256]
    hipLaunchKernelGGL((gemm_mfma<false, true>), dim3(NSEQ / 128, 4), dim3(512), 0, stream,
                       latents, 1024, bpack1, 32, b_proj, ctxb, 256, 1024);
    // latg(f32) = ctx @ W_ih[:,256:512]^T + b_ih   [8192][768]
    hipLaunchKernelGGL((gemm_mfma<true, false>), dim3(NSEQ / 128, 12), dim3(512), 0, stream,
                       ctxb, 256, bpack2, 8, b_ih, latg, 768, 256);

    // ---- per-chunk: fused scan -> head GEMM (stream-ordered) ----
    for (int c = 0; c < nch; ++c) {
        const int seq0 = c * SPC;
        hipLaunchKernelGGL(gru_scan_fused, dim3(SPC / 32), dim3(512), 0, stream,
                           tb, latg, premixB, wpackG, b_hh, hh_c, seq0);
        // logits = h_hist @ W_head^T + b_head    [SPC*16][256]
        hipLaunchKernelGGL((gemm_mfma<true, false>), dim3(SPC * PATCHL / 128, 4), dim3(512), 0, stream,
                           hh_c, 256, bpackH, 8, b_head,
                           out + (size_t)seq0 * PATCHL * VOCABN, 256, 256);
    }
}

// Round 10
// 355.520 us; speedup vs baseline: 1.9114x; 1.1451x over previous
//
#include <hip/hip_runtime.h>
#include <math.h>

// Problem constants
#define NSEQ 8192          // B*N
#define PATCHL 16
#define HIDN 256
#define VOCABN 256

typedef __attribute__((ext_vector_type(4))) float f32x4;
typedef __attribute__((ext_vector_type(8))) short bf16x8;   // 8 bf16 = 4 VGPRs

__device__ __forceinline__ unsigned short f2bf(float f) {
    unsigned int x = __float_as_uint(f);
    unsigned int r = (x + 0x7fffu + ((x >> 16) & 1u)) >> 16;
    return (unsigned short)r;
}
__device__ __forceinline__ float bf2f(unsigned short b) {
    return __uint_as_float(((unsigned int)b) << 16);
}
__device__ __forceinline__ float sigf(float x)   { return 1.f / (1.f + __expf(-x)); }
__device__ __forceinline__ float tanhf_(float x) { return 2.f / (1.f + __expf(-2.f * x)) - 1.f; }

// ---------------------------------------------------------------------------
// Fragment-order bf16 pack of a weight matrix slice (MFMA B operand).
// ---------------------------------------------------------------------------
__global__ __launch_bounds__(256)
void pack_frag(const float* __restrict__ src, int ld, int col0, int nks,
               unsigned short* __restrict__ dst)
{
    const int g = blockIdx.x * 256 + threadIdx.x;
    const int lane = g & 63;
    const int ks = (g / 64) % nks;
    const int T  = g / (64 * nks);
    const float* s = src + (size_t)(T * 16 + (lane & 15)) * ld + col0 + ks * 32 + ((lane >> 4) & 3) * 8;
    unsigned int q[4];
#pragma unroll
    for (int j = 0; j < 4; j++) {
        unsigned int lo = f2bf(s[2 * j]);
        unsigned int hi = f2bf(s[2 * j + 1]);
        q[j] = lo | (hi << 16);
    }
    uint4 v; v.x = q[0]; v.y = q[1]; v.z = q[2]; v.w = q[3];
    *(uint4*)(dst + (size_t)g * 8) = v;
}

// ---------------------------------------------------------------------------
// bf16 MFMA GEMM: C[m][n] = sum_k A[m][k] * W[n][k] (+bias[n])
// BM=128 BN=64 BK=64, 512 threads (8 waves). Verified rounds 3-9.
// OUT_MODE: 0 = f32 row-major [m][ldc], 1 = bf16 row-major [m][ldc],
//           2 = bf16 gate4 [m][1024] at (n&255)*4 + (n>>8)  (r,z,n interleave)
// ---------------------------------------------------------------------------
template<bool ASRC_BF16, int OUT_MODE>
__global__ __launch_bounds__(512)
void gemm_mfma(const void* __restrict__ Asrc, int lda,
               const unsigned short* __restrict__ bpack, int nks_total,
               const float* __restrict__ bias, void* __restrict__ Cdst, int ldc,
               int K)
{
    const int tid = threadIdx.x;
    const int w = tid >> 6, lane = tid & 63;
    const int l15 = lane & 15, kg = (lane >> 4) & 3;
    const int bm = blockIdx.x * 128, bn = blockIdx.y * 64;

    __shared__ unsigned short As[2][128 * 64];

    const int srow = tid >> 2;           // 0..127
    const int scol = (tid & 3) * 16;     // 0,16,32,48
    const int nkt = K / 64;

    f32x4 acc[4];
#pragma unroll
    for (int nt = 0; nt < 4; nt++) acc[nt] = 0.f;

    const int wb0 = srow * 128 + ((scol * 2) ^ ((srow & 7) << 4));
    const int wb1 = srow * 128 + ((scol * 2 + 16) ^ ((srow & 7) << 4));

#define STAGE(kt, buf) do {                                                         \
        const int gk = (kt) * 64 + scol;                                            \
        unsigned short tmp[16];                                                     \
        if (ASRC_BF16) {                                                            \
            const unsigned short* A = (const unsigned short*)Asrc;                  \
            *(uint4*)(tmp)     = *(const uint4*)(A + (size_t)(bm + srow) * lda + gk);      \
            *(uint4*)(tmp + 8) = *(const uint4*)(A + (size_t)(bm + srow) * lda + gk + 8);  \
        } else {                                                                    \
            const float* A = (const float*)Asrc;                                    \
            const float4 a0 = *(const float4*)(A + (size_t)(bm + srow) * lda + gk);       \
            const float4 a1 = *(const float4*)(A + (size_t)(bm + srow) * lda + gk + 4);   \
            const float4 a2 = *(const float4*)(A + (size_t)(bm + srow) * lda + gk + 8);   \
            const float4 a3 = *(const float4*)(A + (size_t)(bm + srow) * lda + gk + 12);  \
            tmp[0] = f2bf(a0.x);  tmp[1] = f2bf(a0.y);  tmp[2] = f2bf(a0.z);  tmp[3] = f2bf(a0.w);   \
            tmp[4] = f2bf(a1.x);  tmp[5] = f2bf(a1.y);  tmp[6] = f2bf(a1.z);  tmp[7] = f2bf(a1.w);   \
            tmp[8] = f2bf(a2.x);  tmp[9] = f2bf(a2.y);  tmp[10] = f2bf(a2.z); tmp[11] = f2bf(a2.w);  \
            tmp[12] = f2bf(a3.x); tmp[13] = f2bf(a3.y); tmp[14] = f2bf(a3.z); tmp[15] = f2bf(a3.w);  \
        }                                                                           \
        *(uint4*)((char*)As[buf] + wb0) = *(uint4*)tmp;                             \
        *(uint4*)((char*)As[buf] + wb1) = *(uint4*)(tmp + 8);                       \
    } while (0)

    STAGE(0, 0);
    __syncthreads();

    for (int kt = 0; kt < nkt; ++kt) {
        if (kt + 1 < nkt) STAGE(kt + 1, (kt + 1) & 1);
        const unsigned short* buf = As[kt & 1];
        const int row = w * 16 + l15;
#pragma unroll
        for (int ks = 0; ks < 2; ++ks) {
            const int bo = row * 128 + (((ks * 64) + kg * 16) ^ ((row & 7) << 4));
            const bf16x8 a = *(const bf16x8*)((const char*)buf + bo);
#pragma unroll
            for (int nt = 0; nt < 4; ++nt) {
                const int T = blockIdx.y * 4 + nt;
                const bf16x8 b = *(const bf16x8*)(bpack + (((size_t)T * nks_total + (kt * 2 + ks)) * 64 + lane) * 8);
                acc[nt] = __builtin_amdgcn_mfma_f32_16x16x32_bf16(a, b, acc[nt], 0, 0, 0);
            }
        }
        __syncthreads();
    }
#undef STAGE

#pragma unroll
    for (int nt = 0; nt < 4; ++nt) {
        const int n = bn + nt * 16 + l15;
        const float bv = bias ? bias[n] : 0.f;
#pragma unroll
        for (int rr = 0; rr < 4; ++rr) {
            const int m = bm + w * 16 + kg * 4 + rr;
            const float v = acc[nt][rr] + bv;
            if (OUT_MODE == 0)      ((float*)Cdst)[(size_t)m * ldc + n] = v;
            else if (OUT_MODE == 1) ((unsigned short*)Cdst)[(size_t)m * ldc + n] = f2bf(v);
            else                    ((unsigned short*)Cdst)[(size_t)m * 1024 + (n & 255) * 4 + (n >> 8)] = f2bf(v);
        }
    }
}

// ---------------------------------------------------------------------------
// Fused GRU scan. 32 seqs/block, 512 threads, 1 block/CU (150 KB LDS).
// r7-r9 showed a hard 128-VGPR allocator ceiling -> the 48-reg latg hoist
// spilled ~140 MB scratch. Fix: latg lives in LDS (LG, gate4 bf16, loaded
// once/block) and premix staged per step in the same gate4 layout, so gate
// reads are single ds_read_b64 per (seq,unit). Payload now ~115 VGPR.
// ---------------------------------------------------------------------------
#define G4S 1032   // gate4 row stride in shorts (1024 + 8 pad)
__global__ __launch_bounds__(512)
void gru_scan_fused(const int* __restrict__ bytes,          // [NSEQ*16]
                    const unsigned short* __restrict__ latg4,   // [NSEQ][1024] gate4 bf16 (incl b_ih)
                    const unsigned short* __restrict__ pmx4,    // [256][1024] gate4 bf16
                    const unsigned short* __restrict__ wpack,   // 48 gate tiles
                    const float* __restrict__ b_hh,         // [768]
                    unsigned short* __restrict__ hh,        // [SPC*16][256] bf16
                    int seq0)
{
    const int tid  = threadIdx.x;
    const int w    = tid >> 6;
    const int lane = tid & 63;
    const int l15  = lane & 15;
    const int kg   = (lane >> 4) & 3;
    const int s0l  = blockIdx.x * 32;            // chunk-local
    const int s0g  = seq0 + s0l;                 // global

    __shared__ unsigned short PMs[32 * G4S];     // 66 KB
    __shared__ unsigned short LG[32 * G4S];      // 66 KB
    __shared__ unsigned short H[32 * 256];       // 16 KB
    __shared__ int BYs[512];                     // 2 KB

    BYs[tid] = bytes[(size_t)s0g * PATCHL + tid];

    // latg (step-invariant) -> LDS once, coalesced uint4 loads
#pragma unroll
    for (int j = 0; j < 8; ++j) {
        const int idx = j * 512 + tid;           // uint4 index; 128 per row
        const int row = idx >> 7, col = idx & 127;
        *(uint4*)(LG + row * G4S + col * 8) =
            *(const uint4*)(latg4 + (size_t)(s0g + row) * 1024 + col * 8);
    }

    float bhr[2], bhz[2], bhn[2];
#pragma unroll
    for (int nt = 0; nt < 2; nt++) {
        const int u = w * 32 + nt * 16 + l15;
        bhr[nt] = b_hh[u]; bhz[nt] = b_hh[256 + u]; bhn[nt] = b_hh[512 + u];
    }

    float hreg[2][2][4];
#pragma unroll
    for (int mt = 0; mt < 2; mt++)
#pragma unroll
        for (int nt = 0; nt < 2; nt++)
#pragma unroll
            for (int rr = 0; rr < 4; rr++) hreg[mt][nt][rr] = 0.f;

    __syncthreads();    // BYs + LG ready

    for (int p = 0; p < PATCHL; ++p) {
        // ---- 1. stage premix gate4 rows for this step's bytes (L2 -> LDS) ----
#pragma unroll
        for (int j = 0; j < 8; ++j) {
            const int idx = j * 512 + tid;       // uint4 index; 128 per row
            const int row = idx >> 7, col = idx & 127;
            const int bv = p ? BYs[row * PATCHL + p - 1] : 0;
            *(uint4*)(PMs + row * G4S + col * 8) =
                *(const uint4*)(pmx4 + (size_t)bv * 1024 + col * 8);
        }

        // ---- 2. coalesced hh write of h(p-1) (reads H, pre-overwrite) ----
        if (p) {
#pragma unroll
            for (int rj = 0; rj < 4; ++rj) {
                const int row = w * 4 + rj;
                const int boff = (lane * 8) ^ ((row & 7) << 4);   // un-swizzle
                const ushort4 v = *(const ushort4*)((const char*)(H + row * 256) + boff);
                *(ushort4*)(hh + ((size_t)(s0l + row) * PATCHL + (p - 1)) * 256 + lane * 4) = v;
            }
        }

        // ---- 3. recurrence: hg = h(p-1) @ W_hh^T ----
        f32x4 accr[2][2], accz[2][2], accn[2][2];
#pragma unroll
        for (int mt = 0; mt < 2; mt++)
#pragma unroll
            for (int nt = 0; nt < 2; nt++) {
                accr[mt][nt] = 0.f; accz[mt][nt] = 0.f; accn[mt][nt] = 0.f;
            }
        if (p != 0) {
#pragma unroll
            for (int ks = 0; ks < 8; ++ks) {
                bf16x8 a[2];
#pragma unroll
                for (int mt = 0; mt < 2; mt++) {
                    const int s = mt * 16 + l15;
                    const int off = (ks * 64 + kg * 16) ^ ((s & 7) << 4);
                    a[mt] = *(const bf16x8*)(H + s * 256 + (off >> 1));
                }
#pragma unroll
                for (int nt = 0; nt < 2; nt++) {
                    const int tb = w * 2 + nt;
                    const bf16x8 br = *(const bf16x8*)(wpack + (((size_t)(tb)      * 8 + ks) * 64 + lane) * 8);
                    const bf16x8 bz = *(const bf16x8*)(wpack + (((size_t)(16 + tb) * 8 + ks) * 64 + lane) * 8);
                    const bf16x8 bn = *(const bf16x8*)(wpack + (((size_t)(32 + tb) * 8 + ks) * 64 + lane) * 8);
#pragma unroll
                    for (int mt = 0; mt < 2; mt++) {
                        accr[mt][nt] = __builtin_amdgcn_mfma_f32_16x16x32_bf16(a[mt], br, accr[mt][nt], 0, 0, 0);
                        accz[mt][nt] = __builtin_amdgcn_mfma_f32_16x16x32_bf16(a[mt], bz, accz[mt][nt], 0, 0, 0);
                        accn[mt][nt] = __builtin_amdgcn_mfma_f32_16x16x32_bf16(a[mt], bn, accn[mt][nt], 0, 0, 0);
                    }
                }
            }
        }
        __syncthreads();   // PMs staged; all H reads (copy + MFMA) complete

        // ---- 5. gates + state update; write h(p) into H ----
#pragma unroll
        for (int mt = 0; mt < 2; mt++)
#pragma unroll
            for (int nt = 0; nt < 2; nt++) {
                const int u = w * 32 + nt * 16 + l15;
#pragma unroll
                for (int rr = 0; rr < 4; rr++) {
                    const int sl = mt * 16 + kg * 4 + rr;
                    const ushort4 pm4 = *(const ushort4*)(PMs + sl * G4S + u * 4);
                    const ushort4 lg4 = *(const ushort4*)(LG  + sl * G4S + u * 4);
                    const float xr = bf2f(lg4.x) + bf2f(pm4.x) + bhr[nt];
                    const float xz = bf2f(lg4.y) + bf2f(pm4.y) + bhz[nt];
                    const float xn = bf2f(lg4.z) + bf2f(pm4.z);
                    const float r = sigf(xr + accr[mt][nt][rr]);
                    const float z = sigf(xz + accz[mt][nt][rr]);
                    const float n = tanhf_(xn + r * (accn[mt][nt][rr] + bhn[nt]));
                    const float hn_ = (1.f - z) * n + z * hreg[mt][nt][rr];
                    hreg[mt][nt][rr] = hn_;
                    const int bo = (2 * u) ^ ((sl & 7) << 4);
                    H[sl * 256 + (bo >> 1)] = f2bf(hn_);
                }
            }
        __syncthreads();   // h(p) visible
    }

    // ---- final hh write for p = 15 ----
#pragma unroll
    for (int rj = 0; rj < 4; ++rj) {
        const int row = w * 4 + rj;
        const int boff = (lane * 8) ^ ((row & 7) << 4);
        const ushort4 v = *(const ushort4*)((const char*)(H + row * 256) + boff);
        *(ushort4*)(hh + ((size_t)(s0l + row) * PATCHL + (PATCHL - 1)) * 256 + lane * 4) = v;
    }
}

// ---------------------------------------------------------------------------
extern "C" void kernel_launch(void* const* d_in, const int* in_sizes, int n_in,
                              void* d_out, int out_size, void* d_ws, size_t ws_size,
                              hipStream_t stream)
{
    const float* latents = (const float*)d_in[0];   // [8192][1024]
    const int*   tb      = (const int*)d_in[1];     // [8192*16]
    const float* W_proj  = (const float*)d_in[2];   // [256][1024]
    const float* b_proj  = (const float*)d_in[3];   // [256]
    const float* emb     = (const float*)d_in[4];   // [256][256]
    const float* W_ih    = (const float*)d_in[5];   // [768][512]
    const float* W_hh    = (const float*)d_in[6];   // [768][256]
    const float* b_ih    = (const float*)d_in[7];   // [768]
    const float* b_hh    = (const float*)d_in[8];   // [768]
    const float* W_head  = (const float*)d_in[9];   // [256][256]
    const float* b_head  = (const float*)d_in[10];  // [256]
    float* out = (float*)d_out;

    // ---- workspace layout (bytes) ----
    char* w = (char*)d_ws;
    unsigned short* latg4   = (unsigned short*)w;          w += (size_t)NSEQ * 1024 * 2;    // 16.8 MB
    unsigned short* ctxb    = (unsigned short*)w;          w += (size_t)NSEQ * HIDN * 2;    // 4.2 MB
    unsigned short* pmx4    = (unsigned short*)w;          w += 256 * 1024 * 2;             // 512 KB
    unsigned short* bpack1  = (unsigned short*)w;          w += 16 * 32 * 64 * 8 * 2;
    unsigned short* bpack2  = (unsigned short*)w;          w += 48 * 8 * 64 * 8 * 2;
    unsigned short* bpack3  = (unsigned short*)w;          w += 48 * 8 * 64 * 8 * 2;
    unsigned short* wpackG  = (unsigned short*)w;          w += 48 * 8 * 64 * 8 * 2;        // gates
    unsigned short* bpackH  = (unsigned short*)w;          w += 16 * 8 * 64 * 8 * 2;        // head
    unsigned short* hh_c    = (unsigned short*)w;
    const size_t fixed_bytes = (size_t)(w - (char*)d_ws);
    const size_t chunk_full  = (size_t)NSEQ * PATCHL * 256 * 2;          // hh = 67 MB

    int nch = 1;
    while (nch < 16 && fixed_bytes + chunk_full / nch > ws_size) nch <<= 1;
    const int SPC = NSEQ / nch;                    // seqs per chunk

    // ---- weight packs (fragment-ordered bf16) ----
    hipLaunchKernelGGL(pack_frag, dim3(128), dim3(256), 0, stream, W_proj, 1024, 0, 32, bpack1);
    hipLaunchKernelGGL(pack_frag, dim3(96),  dim3(256), 0, stream, W_ih,   512, 256, 8, bpack2);
    hipLaunchKernelGGL(pack_frag, dim3(96),  dim3(256), 0, stream, W_ih,   512, 0,   8, bpack3);
    hipLaunchKernelGGL(pack_frag, dim3(96),  dim3(256), 0, stream, W_hh,   256, 0,   8, wpackG);
    hipLaunchKernelGGL(pack_frag, dim3(32),  dim3(256), 0, stream, W_head, 256, 0,   8, bpackH);

    // pmx4(gate4 bf16) = emb @ W_ih[:,0:256]^T     [256][1024]
    hipLaunchKernelGGL((gemm_mfma<false, 2>), dim3(2, 12), dim3(512), 0, stream,
                       emb, 256, bpack3, 8, nullptr, pmx4, 1024, 256);
    // ctx(bf16) = latents @ W_proj^T + b_proj      [8192][256]
    hipLaunchKernelGGL((gemm_mfma<false, 1>), dim3(NSEQ / 128, 4), dim3(512), 0, stream,
                       latents, 1024, bpack1, 32, b_proj, ctxb, 256, 1024);
    // latg4(gate4 bf16) = ctx @ W_ih[:,256:512]^T + b_ih   [8192][1024]
    hipLaunchKernelGGL((gemm_mfma<true, 2>), dim3(NSEQ / 128, 12), dim3(512), 0, stream,
                       ctxb, 256, bpack2, 8, b_ih, latg4, 1024, 256);

    // ---- per-chunk: fused scan -> head GEMM (stream-ordered) ----
    for (int c = 0; c < nch; ++c) {
        const int seq0 = c * SPC;
        hipLaunchKernelGGL(gru_scan_fused, dim3(SPC / 32), dim3(512), 0, stream,
                           tb, latg4, pmx4, wpackG, b_hh, hh_c, seq0);
        // logits = h_hist @ W_head^T + b_head    [SPC*16][256]
        hipLaunchKernelGGL((gemm_mfma<true, 0>), dim3(SPC * PATCHL / 128, 4), dim3(512), 0, stream,
                           hh_c, 256, bpackH, 8, b_head,
                           out + (size_t)seq0 * PATCHL * VOCABN, 256, 256);
    }
}

// Round 11
// 343.672 us; speedup vs baseline: 1.9773x; 1.0345x over previous
//
#include <hip/hip_runtime.h>
#include <math.h>

// Problem constants
#define NSEQ 8192          // B*N
#define PATCHL 16
#define HIDN 256
#define VOCABN 256

typedef __attribute__((ext_vector_type(4))) float f32x4;
typedef __attribute__((ext_vector_type(8))) short bf16x8;   // 8 bf16 = 4 VGPRs

__device__ __forceinline__ unsigned short f2bf(float f) {
    unsigned int x = __float_as_uint(f);
    unsigned int r = (x + 0x7fffu + ((x >> 16) & 1u)) >> 16;
    return (unsigned short)r;
}
__device__ __forceinline__ float bf2f(unsigned short b) {
    return __uint_as_float(((unsigned int)b) << 16);
}
__device__ __forceinline__ float sigf(float x)   { return 1.f / (1.f + __expf(-x)); }
__device__ __forceinline__ float tanhf_(float x) { return 2.f / (1.f + __expf(-2.f * x)) - 1.f; }

// ---------------------------------------------------------------------------
// Fragment-order bf16 pack of a weight matrix slice (MFMA B operand).
// ---------------------------------------------------------------------------
__global__ __launch_bounds__(256)
void pack_frag(const float* __restrict__ src, int ld, int col0, int nks,
               unsigned short* __restrict__ dst)
{
    const int g = blockIdx.x * 256 + threadIdx.x;
    const int lane = g & 63;
    const int ks = (g / 64) % nks;
    const int T  = g / (64 * nks);
    const float* s = src + (size_t)(T * 16 + (lane & 15)) * ld + col0 + ks * 32 + ((lane >> 4) & 3) * 8;
    unsigned int q[4];
#pragma unroll
    for (int j = 0; j < 4; j++) {
        unsigned int lo = f2bf(s[2 * j]);
        unsigned int hi = f2bf(s[2 * j + 1]);
        q[j] = lo | (hi << 16);
    }
    uint4 v; v.x = q[0]; v.y = q[1]; v.z = q[2]; v.w = q[3];
    *(uint4*)(dst + (size_t)g * 8) = v;
}

// ---------------------------------------------------------------------------
// bf16 MFMA GEMM: C[m][n] = sum_k A[m][k] * W[n][k] (+bias[n])
// BM=128 BN=64 BK=64, 512 threads (8 waves). Verified rounds 3-10.
// OUT_MODE: 0 = f32 row-major, 1 = bf16 row-major, 2 = bf16 gate4 interleave.
// ---------------------------------------------------------------------------
template<bool ASRC_BF16, int OUT_MODE>
__global__ __launch_bounds__(512)
void gemm_mfma(const void* __restrict__ Asrc, int lda,
               const unsigned short* __restrict__ bpack, int nks_total,
               const float* __restrict__ bias, void* __restrict__ Cdst, int ldc,
               int K)
{
    const int tid = threadIdx.x;
    const int w = tid >> 6, lane = tid & 63;
    const int l15 = lane & 15, kg = (lane >> 4) & 3;
    const int bm = blockIdx.x * 128, bn = blockIdx.y * 64;

    __shared__ unsigned short As[2][128 * 64];

    const int srow = tid >> 2;           // 0..127
    const int scol = (tid & 3) * 16;     // 0,16,32,48
    const int nkt = K / 64;

    f32x4 acc[4];
#pragma unroll
    for (int nt = 0; nt < 4; nt++) acc[nt] = 0.f;

    const int wb0 = srow * 128 + ((scol * 2) ^ ((srow & 7) << 4));
    const int wb1 = srow * 128 + ((scol * 2 + 16) ^ ((srow & 7) << 4));

#define STAGE(kt, buf) do {                                                         \
        const int gk = (kt) * 64 + scol;                                            \
        unsigned short tmp[16];                                                     \
        if (ASRC_BF16) {                                                            \
            const unsigned short* A = (const unsigned short*)Asrc;                  \
            *(uint4*)(tmp)     = *(const uint4*)(A + (size_t)(bm + srow) * lda + gk);      \
            *(uint4*)(tmp + 8) = *(const uint4*)(A + (size_t)(bm + srow) * lda + gk + 8);  \
        } else {                                                                    \
            const float* A = (const float*)Asrc;                                    \
            const float4 a0 = *(const float4*)(A + (size_t)(bm + srow) * lda + gk);       \
            const float4 a1 = *(const float4*)(A + (size_t)(bm + srow) * lda + gk + 4);   \
            const float4 a2 = *(const float4*)(A + (size_t)(bm + srow) * lda + gk + 8);   \
            const float4 a3 = *(const float4*)(A + (size_t)(bm + srow) * lda + gk + 12);  \
            tmp[0] = f2bf(a0.x);  tmp[1] = f2bf(a0.y);  tmp[2] = f2bf(a0.z);  tmp[3] = f2bf(a0.w);   \
            tmp[4] = f2bf(a1.x);  tmp[5] = f2bf(a1.y);  tmp[6] = f2bf(a1.z);  tmp[7] = f2bf(a1.w);   \
            tmp[8] = f2bf(a2.x);  tmp[9] = f2bf(a2.y);  tmp[10] = f2bf(a2.z); tmp[11] = f2bf(a2.w);  \
            tmp[12] = f2bf(a3.x); tmp[13] = f2bf(a3.y); tmp[14] = f2bf(a3.z); tmp[15] = f2bf(a3.w);  \
        }                                                                           \
        *(uint4*)((char*)As[buf] + wb0) = *(uint4*)tmp;                             \
        *(uint4*)((char*)As[buf] + wb1) = *(uint4*)(tmp + 8);                       \
    } while (0)

    STAGE(0, 0);
    __syncthreads();

    for (int kt = 0; kt < nkt; ++kt) {
        if (kt + 1 < nkt) STAGE(kt + 1, (kt + 1) & 1);
        const unsigned short* buf = As[kt & 1];
        const int row = w * 16 + l15;
#pragma unroll
        for (int ks = 0; ks < 2; ++ks) {
            const int bo = row * 128 + (((ks * 64) + kg * 16) ^ ((row & 7) << 4));
            const bf16x8 a = *(const bf16x8*)((const char*)buf + bo);
#pragma unroll
            for (int nt = 0; nt < 4; ++nt) {
                const int T = blockIdx.y * 4 + nt;
                const bf16x8 b = *(const bf16x8*)(bpack + (((size_t)T * nks_total + (kt * 2 + ks)) * 64 + lane) * 8);
                acc[nt] = __builtin_amdgcn_mfma_f32_16x16x32_bf16(a, b, acc[nt], 0, 0, 0);
            }
        }
        __syncthreads();
    }
#undef STAGE

#pragma unroll
    for (int nt = 0; nt < 4; ++nt) {
        const int n = bn + nt * 16 + l15;
        const float bv = bias ? bias[n] : 0.f;
#pragma unroll
        for (int rr = 0; rr < 4; ++rr) {
            const int m = bm + w * 16 + kg * 4 + rr;
            const float v = acc[nt][rr] + bv;
            if (OUT_MODE == 0)      ((float*)Cdst)[(size_t)m * ldc + n] = v;
            else if (OUT_MODE == 1) ((unsigned short*)Cdst)[(size_t)m * ldc + n] = f2bf(v);
            else                    ((unsigned short*)Cdst)[(size_t)m * 1024 + (n & 255) * 4 + (n >> 8)] = f2bf(v);
        }
    }
}

// ---------------------------------------------------------------------------
// Fused GRU scan, 16 seqs/block, 512 threads, 75.3 KB LDS -> 2 blocks/CU.
// r10 was 1 block/CU: 2 barriers/step serialized every phase, ~85% stall
// (32k cyc/step vs ~5k of work). Two co-resident blocks let one block's
// stage/gate phases overlap the other's MFMA phase. Per-thread work halves
// (8 gate-sets), VGPR ~100 < 128 ceiling -> no spill.
// ---------------------------------------------------------------------------
#define G4S 1032   // gate4 row stride in shorts (1024 + 8 pad)
__global__ __launch_bounds__(512)
void gru_scan_fused(const int* __restrict__ bytes,          // [NSEQ*16]
                    const unsigned short* __restrict__ latg4,   // [NSEQ][1024] gate4 bf16 (incl b_ih)
                    const unsigned short* __restrict__ pmx4,    // [256][1024] gate4 bf16
                    const unsigned short* __restrict__ wpack,   // 48 gate tiles
                    const float* __restrict__ b_hh,         // [768]
                    unsigned short* __restrict__ hh,        // [SPC*16][256] bf16
                    int seq0)
{
    const int tid  = threadIdx.x;
    const int w    = tid >> 6;
    const int lane = tid & 63;
    const int l15  = lane & 15;
    const int kg   = (lane >> 4) & 3;
    const int s0l  = blockIdx.x * 16;            // chunk-local
    const int s0g  = seq0 + s0l;                 // global

    __shared__ unsigned short PMs[16 * G4S];     // 33 KB
    __shared__ unsigned short LG[16 * G4S];      // 33 KB
    __shared__ unsigned short H[16 * 256];       // 8 KB
    __shared__ int BYs[256];                     // 1 KB

    if (tid < 256) BYs[tid] = bytes[(size_t)s0g * PATCHL + tid];

    // latg (step-invariant) -> LDS once, coalesced uint4 loads
#pragma unroll
    for (int j = 0; j < 4; ++j) {
        const int idx = j * 512 + tid;           // uint4 index; 128 per row
        const int row = idx >> 7, col = idx & 127;
        *(uint4*)(LG + row * G4S + col * 8) =
            *(const uint4*)(latg4 + (size_t)(s0g + row) * 1024 + col * 8);
    }

    float bhr[2], bhz[2], bhn[2];
#pragma unroll
    for (int nt = 0; nt < 2; nt++) {
        const int u = w * 32 + nt * 16 + l15;
        bhr[nt] = b_hh[u]; bhz[nt] = b_hh[256 + u]; bhn[nt] = b_hh[512 + u];
    }

    float hreg[2][4];
#pragma unroll
    for (int nt = 0; nt < 2; nt++)
#pragma unroll
        for (int rr = 0; rr < 4; rr++) hreg[nt][rr] = 0.f;

    __syncthreads();    // BYs + LG ready

    for (int p = 0; p < PATCHL; ++p) {
        // ---- 1. stage premix gate4 rows for this step's bytes (L2 -> LDS) ----
#pragma unroll
        for (int j = 0; j < 4; ++j) {
            const int idx = j * 512 + tid;       // uint4 index; 128 per row
            const int row = idx >> 7, col = idx & 127;
            const int bv = p ? BYs[row * PATCHL + p - 1] : 0;
            *(uint4*)(PMs + row * G4S + col * 8) =
                *(const uint4*)(pmx4 + (size_t)bv * 1024 + col * 8);
        }

        // ---- 2. coalesced hh write of h(p-1) (reads H, pre-overwrite) ----
        if (p) {
#pragma unroll
            for (int rj = 0; rj < 2; ++rj) {
                const int row = w * 2 + rj;
                const int boff = (lane * 8) ^ ((row & 7) << 4);   // un-swizzle
                const ushort4 v = *(const ushort4*)((const char*)(H + row * 256) + boff);
                *(ushort4*)(hh + ((size_t)(s0l + row) * PATCHL + (p - 1)) * 256 + lane * 4) = v;
            }
        }

        // ---- 3. recurrence: hg = h(p-1) @ W_hh^T (one M-tile) ----
        f32x4 accr[2], accz[2], accn[2];
#pragma unroll
        for (int nt = 0; nt < 2; nt++) { accr[nt] = 0.f; accz[nt] = 0.f; accn[nt] = 0.f; }
        if (p != 0) {
#pragma unroll
            for (int ks = 0; ks < 8; ++ks) {
                const int s = l15;
                const int off = (ks * 64 + kg * 16) ^ ((s & 7) << 4);
                const bf16x8 a = *(const bf16x8*)(H + s * 256 + (off >> 1));
#pragma unroll
                for (int nt = 0; nt < 2; nt++) {
                    const int tb = w * 2 + nt;
                    const bf16x8 br = *(const bf16x8*)(wpack + (((size_t)(tb)      * 8 + ks) * 64 + lane) * 8);
                    const bf16x8 bz = *(const bf16x8*)(wpack + (((size_t)(16 + tb) * 8 + ks) * 64 + lane) * 8);
                    const bf16x8 bn = *(const bf16x8*)(wpack + (((size_t)(32 + tb) * 8 + ks) * 64 + lane) * 8);
                    accr[nt] = __builtin_amdgcn_mfma_f32_16x16x32_bf16(a, br, accr[nt], 0, 0, 0);
                    accz[nt] = __builtin_amdgcn_mfma_f32_16x16x32_bf16(a, bz, accz[nt], 0, 0, 0);
                    accn[nt] = __builtin_amdgcn_mfma_f32_16x16x32_bf16(a, bn, accn[nt], 0, 0, 0);
                }
            }
        }
        __syncthreads();   // PMs staged; all H reads (copy + MFMA) complete

        // ---- 5. gates + state update; write h(p) into H ----
#pragma unroll
        for (int nt = 0; nt < 2; nt++) {
            const int u = w * 32 + nt * 16 + l15;
#pragma unroll
            for (int rr = 0; rr < 4; rr++) {
                const int sl = kg * 4 + rr;
                const ushort4 pm4 = *(const ushort4*)(PMs + sl * G4S + u * 4);
                const ushort4 lg4 = *(const ushort4*)(LG  + sl * G4S + u * 4);
                const float xr = bf2f(lg4.x) + bf2f(pm4.x) + bhr[nt];
                const float xz = bf2f(lg4.y) + bf2f(pm4.y) + bhz[nt];
                const float xn = bf2f(lg4.z) + bf2f(pm4.z);
                const float r = sigf(xr + accr[nt][rr]);
                const float z = sigf(xz + accz[nt][rr]);
                const float n = tanhf_(xn + r * (accn[nt][rr] + bhn[nt]));
                const float hn_ = (1.f - z) * n + z * hreg[nt][rr];
                hreg[nt][rr] = hn_;
                const int bo = (2 * u) ^ ((sl & 7) << 4);
                H[sl * 256 + (bo >> 1)] = f2bf(hn_);
            }
        }
        __syncthreads();   // h(p) visible
    }

    // ---- final hh write for p = 15 ----
#pragma unroll
    for (int rj = 0; rj < 2; ++rj) {
        const int row = w * 2 + rj;
        const int boff = (lane * 8) ^ ((row & 7) << 4);
        const ushort4 v = *(const ushort4*)((const char*)(H + row * 256) + boff);
        *(ushort4*)(hh + ((size_t)(s0l + row) * PATCHL + (PATCHL - 1)) * 256 + lane * 4) = v;
    }
}

// ---------------------------------------------------------------------------
extern "C" void kernel_launch(void* const* d_in, const int* in_sizes, int n_in,
                              void* d_out, int out_size, void* d_ws, size_t ws_size,
                              hipStream_t stream)
{
    const float* latents = (const float*)d_in[0];   // [8192][1024]
    const int*   tb      = (const int*)d_in[1];     // [8192*16]
    const float* W_proj  = (const float*)d_in[2];   // [256][1024]
    const float* b_proj  = (const float*)d_in[3];   // [256]
    const float* emb     = (const float*)d_in[4];   // [256][256]
    const float* W_ih    = (const float*)d_in[5];   // [768][512]
    const float* W_hh    = (const float*)d_in[6];   // [768][256]
    const float* b_ih    = (const float*)d_in[7];   // [768]
    const float* b_hh    = (const float*)d_in[8];   // [768]
    const float* W_head  = (const float*)d_in[9];   // [256][256]
    const float* b_head  = (const float*)d_in[10];  // [256]
    float* out = (float*)d_out;

    // ---- workspace layout (bytes) ----
    char* w = (char*)d_ws;
    unsigned short* latg4   = (unsigned short*)w;          w += (size_t)NSEQ * 1024 * 2;    // 16.8 MB
    unsigned short* ctxb    = (unsigned short*)w;          w += (size_t)NSEQ * HIDN * 2;    // 4.2 MB
    unsigned short* pmx4    = (unsigned short*)w;          w += 256 * 1024 * 2;             // 512 KB
    unsigned short* bpack1  = (unsigned short*)w;          w += 16 * 32 * 64 * 8 * 2;
    unsigned short* bpack2  = (unsigned short*)w;          w += 48 * 8 * 64 * 8 * 2;
    unsigned short* bpack3  = (unsigned short*)w;          w += 48 * 8 * 64 * 8 * 2;
    unsigned short* wpackG  = (unsigned short*)w;          w += 48 * 8 * 64 * 8 * 2;        // gates
    unsigned short* bpackH  = (unsigned short*)w;          w += 16 * 8 * 64 * 8 * 2;        // head
    unsigned short* hh_c    = (unsigned short*)w;
    const size_t fixed_bytes = (size_t)(w - (char*)d_ws);
    const size_t chunk_full  = (size_t)NSEQ * PATCHL * 256 * 2;          // hh = 67 MB

    int nch = 1;
    while (nch < 16 && fixed_bytes + chunk_full / nch > ws_size) nch <<= 1;
    const int SPC = NSEQ / nch;                    // seqs per chunk

    // ---- weight packs (fragment-ordered bf16) ----
    hipLaunchKernelGGL(pack_frag, dim3(128), dim3(256), 0, stream, W_proj, 1024, 0, 32, bpack1);
    hipLaunchKernelGGL(pack_frag, dim3(96),  dim3(256), 0, stream, W_ih,   512, 256, 8, bpack2);
    hipLaunchKernelGGL(pack_frag, dim3(96),  dim3(256), 0, stream, W_ih,   512, 0,   8, bpack3);
    hipLaunchKernelGGL(pack_frag, dim3(96),  dim3(256), 0, stream, W_hh,   256, 0,   8, wpackG);
    hipLaunchKernelGGL(pack_frag, dim3(32),  dim3(256), 0, stream, W_head, 256, 0,   8, bpackH);

    // pmx4(gate4 bf16) = emb @ W_ih[:,0:256]^T     [256][1024]
    hipLaunchKernelGGL((gemm_mfma<false, 2>), dim3(2, 12), dim3(512), 0, stream,
                       emb, 256, bpack3, 8, nullptr, pmx4, 1024, 256);
    // ctx(bf16) = latents @ W_proj^T + b_proj      [8192][256]
    hipLaunchKernelGGL((gemm_mfma<false, 1>), dim3(NSEQ / 128, 4), dim3(512), 0, stream,
                       latents, 1024, bpack1, 32, b_proj, ctxb, 256, 1024);
    // latg4(gate4 bf16) = ctx @ W_ih[:,256:512]^T + b_ih   [8192][1024]
    hipLaunchKernelGGL((gemm_mfma<true, 2>), dim3(NSEQ / 128, 12), dim3(512), 0, stream,
                       ctxb, 256, bpack2, 8, b_ih, latg4, 1024, 256);

    // ---- per-chunk: fused scan -> head GEMM (stream-ordered) ----
    for (int c = 0; c < nch; ++c) {
        const int seq0 = c * SPC;
        hipLaunchKernelGGL(gru_scan_fused, dim3(SPC / 16), dim3(512), 0, stream,
                           tb, latg4, pmx4, wpackG, b_hh, hh_c, seq0);
        // logits = h_hist @ W_head^T + b_head    [SPC*16][256]
        hipLaunchKernelGGL((gemm_mfma<true, 0>), dim3(SPC * PATCHL / 128, 4), dim3(512), 0, stream,
                           hh_c, 256, bpackH, 8, b_head,
                           out + (size_t)seq0 * PATCHL * VOCABN, 256, 256);
    }
}